// Round 3
// baseline (1803.039 us; speedup 1.0000x reference)
//
#include <hip/hip_runtime.h>

#define NT 4096      // B*L tokens
#define DM 768
#define DI 1536
#define LSEQ 2048
#define NBATCH 2
#define DBCW 80      // dt_rank + 2*n_state
#define DTR 48
#define NS 16

// canonical input segment offsets (elements)
#define O_X    0
#define O_LNW  3145728
#define O_LNB  3146496
#define O_INW  3147264
#define O_CW   5506560
#define O_CB   5512704
#define O_XPW  5514240
#define O_DTW  5637120
#define O_DTB  5710848
#define O_ALOG 5712384
#define O_DPAR 5736960
#define O_OUTW 5738496
#define O_TOT  6918144

typedef __attribute__((ext_vector_type(8))) short short8;
typedef __attribute__((ext_vector_type(4))) float float4v;

__device__ __forceinline__ float bf2f(short s) {
    union { unsigned int u; float f; } c; c.u = ((unsigned int)(unsigned short)s) << 16; return c.f;
}
__device__ __forceinline__ float bflo(unsigned int u) {
    union { unsigned int u; float f; } c; c.u = u << 16; return c.f;
}
__device__ __forceinline__ float bfhi(unsigned int u) {
    union { unsigned int u; float f; } c; c.u = u & 0xffff0000u; return c.f;
}
__device__ __forceinline__ short f2bf(float f) {
    union { unsigned int u; float f; } c; c.f = f;
    unsigned int lsb = (c.u >> 16) & 1u;
    unsigned int r = c.u + 0x7fffu + lsb;
    return (short)(r >> 16);
}
__device__ __forceinline__ float silu(float x) { return x / (1.f + __expf(-x)); }

// ---------------- dtype detection: even-index shorts of x ----------------
// bf16 data: even shorts are bf16 of N(0,1) -> exponent field in [100,140] ~always.
// f32 data: even shorts are float mantissa low bits -> ~uniform (~16% hit rate).
__global__ void detect_kernel(const unsigned short* __restrict__ x, int* __restrict__ flag) {
    int lane = threadIdx.x & 63;
    unsigned short s = x[lane * 2];
    int e = (s >> 7) & 0xFF;
    bool plaus = (e >= 100 && e <= 140);
    unsigned long long m = __ballot(plaus);
    if (lane == 0) *flag = (__popcll(m) >= 32) ? 0 : 1;  // 0=bf16, 1=f32
}

// ---------------- canonicalize all inputs into one bf16 buffer ----------------
__global__ __launch_bounds__(256) void canon_kernel(
    const void* s0, const void* s1, const void* s2, const void* s3,
    const void* s4, const void* s5, const void* s6, const void* s7,
    const void* s8, const void* s9, const void* s10, const void* s11,
    const int* __restrict__ flag, short* __restrict__ canon) {
    int i = blockIdx.x * 256 + threadIdx.x;
    if (i >= O_TOT) return;
    const void* src; int j;
    if      (i < O_LNW)  { src = s0;  j = i; }
    else if (i < O_LNB)  { src = s1;  j = i - O_LNW; }
    else if (i < O_INW)  { src = s2;  j = i - O_LNB; }
    else if (i < O_CW)   { src = s3;  j = i - O_INW; }
    else if (i < O_CB)   { src = s4;  j = i - O_CW; }
    else if (i < O_XPW)  { src = s5;  j = i - O_CB; }
    else if (i < O_DTW)  { src = s6;  j = i - O_XPW; }
    else if (i < O_DTB)  { src = s7;  j = i - O_DTW; }
    else if (i < O_ALOG) { src = s8;  j = i - O_DTB; }
    else if (i < O_DPAR) { src = s9;  j = i - O_ALOG; }
    else if (i < O_OUTW) { src = s10; j = i - O_DPAR; }
    else                 { src = s11; j = i - O_OUTW; }
    short v;
    if (*flag) v = f2bf(((const float*)src)[j]);
    else       v = ((const short*)src)[j];
    canon[i] = v;
}

// ---------------- LayerNorm: one wave per token ----------------
__global__ __launch_bounds__(256) void ln_kernel(const short* __restrict__ x,
                                                 const short* __restrict__ w,
                                                 const short* __restrict__ b,
                                                 short* __restrict__ xn) {
    const int wave = threadIdx.x >> 6, lane = threadIdx.x & 63;
    const int token = blockIdx.x * 4 + wave;
    const short* xr = x + (size_t)token * DM;
    short* xo = xn + (size_t)token * DM;
    float vals[12];
    float s = 0.f, s2 = 0.f;
#pragma unroll
    for (int j = 0; j < 6; j++) {
        unsigned int u = *(const unsigned int*)(xr + lane * 2 + j * 128);
        float f0 = bflo(u), f1 = bfhi(u);
        vals[2 * j] = f0; vals[2 * j + 1] = f1;
        s += f0 + f1; s2 += f0 * f0 + f1 * f1;
    }
#pragma unroll
    for (int off = 1; off < 64; off <<= 1) {
        s += __shfl_xor(s, off);
        s2 += __shfl_xor(s2, off);
    }
    const float mu = s * (1.f / DM);
    const float var = s2 * (1.f / DM) - mu * mu;
    const float rs = rsqrtf(var + 1e-5f);
#pragma unroll
    for (int j = 0; j < 6; j++) {
        int e = lane * 2 + j * 128;
        unsigned int uw = *(const unsigned int*)(w + e);
        unsigned int ub = *(const unsigned int*)(b + e);
        float o0 = (vals[2 * j] - mu) * rs * bflo(uw) + bflo(ub);
        float o1 = (vals[2 * j + 1] - mu) * rs * bfhi(uw) + bfhi(ub);
        unsigned int pk = (unsigned int)(unsigned short)f2bf(o0) |
                          ((unsigned int)(unsigned short)f2bf(o1) << 16);
        *(unsigned int*)(xo + e) = pk;
    }
}

// ---------------- Generic bf16 MFMA GEMM: C[m,n] = sum_k A[m,k]*B[n,k] ----------------
// MODE 0: split epilogue (in_proj): n<DI -> outS bf16 (stride DI), else outS2 bf16 (stride DI)
// MODE 1: f32 out, stride N, bounds-check n<N (x_proj, N=80)
// MODE 2: final out, stride N: *oflag ? f32 to outF : bf16 to outS (out_proj)
template <int MODE>
__global__ __launch_bounds__(256) void gemm_bt(const short* __restrict__ A,
                                               const short* __restrict__ B,
                                               int M, int N, int K,
                                               float* __restrict__ outF,
                                               short* __restrict__ outS,
                                               short* __restrict__ outS2,
                                               const int* __restrict__ oflag) {
    __shared__ short As[64 * 40];
    __shared__ short Bs[64 * 40];
    const int tid = threadIdx.x;
    const int mBase = blockIdx.y * 64;
    const int nBase = blockIdx.x * 64;
    const int lrow = tid >> 2;
    const int lcol = (tid & 3) * 8;
    const int wave = tid >> 6;
    const int lane = tid & 63;
    const int l15 = lane & 15;
    const int quad = lane >> 4;
    const int wm = (wave >> 1) * 32;
    const int wn = (wave & 1) * 32;

    float4v acc[2][2] = {};

    const bool bvalid = (nBase + lrow) < N;
    const short* aptr = A + (size_t)(mBase + lrow) * K + lcol;
    const short* bptr = B + (size_t)(nBase + lrow) * K + lcol;
    const short8 bz = {0, 0, 0, 0, 0, 0, 0, 0};

    for (int k0 = 0; k0 < K; k0 += 32) {
        short8 av = *(const short8*)(aptr + k0);
        short8 bv = bvalid ? *(const short8*)(bptr + k0) : bz;
        __syncthreads();
        *(short8*)&As[lrow * 40 + lcol] = av;
        *(short8*)&Bs[lrow * 40 + lcol] = bv;
        __syncthreads();
        short8 a0 = *(const short8*)&As[(wm + l15) * 40 + quad * 8];
        short8 a1 = *(const short8*)&As[(wm + 16 + l15) * 40 + quad * 8];
        short8 b0 = *(const short8*)&Bs[(wn + l15) * 40 + quad * 8];
        short8 b1 = *(const short8*)&Bs[(wn + 16 + l15) * 40 + quad * 8];
        acc[0][0] = __builtin_amdgcn_mfma_f32_16x16x32_bf16(a0, b0, acc[0][0], 0, 0, 0);
        acc[0][1] = __builtin_amdgcn_mfma_f32_16x16x32_bf16(a0, b1, acc[0][1], 0, 0, 0);
        acc[1][0] = __builtin_amdgcn_mfma_f32_16x16x32_bf16(a1, b0, acc[1][0], 0, 0, 0);
        acc[1][1] = __builtin_amdgcn_mfma_f32_16x16x32_bf16(a1, b1, acc[1][1], 0, 0, 0);
    }

    const bool outf32 = (MODE == 2) ? (*oflag != 0) : false;
#pragma unroll
    for (int i = 0; i < 2; i++)
#pragma unroll
        for (int j = 0; j < 2; j++)
#pragma unroll
            for (int r = 0; r < 4; r++) {
                int m = mBase + wm + i * 16 + quad * 4 + r;
                int n = nBase + wn + j * 16 + l15;
                float v = acc[i][j][r];
                if (MODE == 0) {
                    if (n < DI) outS[(size_t)m * DI + n] = f2bf(v);
                    else outS2[(size_t)m * DI + (n - DI)] = f2bf(v);
                } else if (MODE == 1) {
                    if (n < N) outF[(size_t)m * N + n] = v;
                } else {
                    if (outf32) outF[(size_t)m * N + n] = v;
                    else outS[(size_t)m * N + n] = f2bf(v);
                }
            }
}

// ---------------- depthwise causal conv (taps=4) + SiLU ----------------
__global__ __launch_bounds__(256) void conv_kernel(const short* __restrict__ xin,
                                                   const short* __restrict__ cw,
                                                   const short* __restrict__ cb,
                                                   short* __restrict__ ub) {
    const int idx = blockIdx.x * 256 + threadIdx.x;  // over NT*DI, exact
    const int d = idx % DI;
    const int t = idx / DI;
    const int l = t % LSEQ;
    float s = bf2f(cb[d]);
#pragma unroll
    for (int j = 0; j < 4; j++) {
        int lj = l - 3 + j;
        if (lj >= 0) s += bf2f(xin[(size_t)(t - 3 + j) * DI + d]) * bf2f(cw[d * 4 + j]);
    }
    float u = silu(s);
    ub[idx] = f2bf(u);
}

// ---------------- dt_proj (K=48) + softplus ----------------
__global__ __launch_bounds__(256) void dtproj_kernel(const float* __restrict__ dbc,
                                                     const short* __restrict__ dw,
                                                     const short* __restrict__ db,
                                                     float* __restrict__ delta) {
    const int m = blockIdx.x;
    __shared__ float dts[DTR];
    if (threadIdx.x < DTR) dts[threadIdx.x] = dbc[(size_t)m * DBCW + threadIdx.x];
    __syncthreads();
    for (int d = threadIdx.x; d < DI; d += 256) {
        const short* wr = dw + (size_t)d * DTR;
        float s = bf2f(db[d]);
#pragma unroll
        for (int k = 0; k < DTR; k += 2) {
            unsigned int u = *(const unsigned int*)(wr + k);
            s += dts[k] * bflo(u) + dts[k + 1] * bfhi(u);
        }
        float sp = (s > 20.f) ? s : log1pf(__expf(s));
        delta[(size_t)m * DI + d] = sp;
    }
}

// ---------------- selective scan: lane = (n, d-sub), 16 d per block per batch ----------------
__global__ __launch_bounds__(256) void scan_kernel(const float* __restrict__ delta,
                                                   const short* __restrict__ ub,
                                                   const float* __restrict__ dbc,
                                                   const short* __restrict__ alog,
                                                   const short* __restrict__ dpar,
                                                   const short* __restrict__ resb,
                                                   short* __restrict__ yb) {
    const int wave = threadIdx.x >> 6, lane = threadIdx.x & 63;
    const int n = lane & 15, dsub = lane >> 4;
    const int b = blockIdx.x / 96;
    const int d = (blockIdx.x % 96) * 16 + wave * 4 + dsub;
    const float Av = -__expf(bf2f(alog[d * NS + n]));
    const float Al2 = Av * 1.44269504f;
    const float Dd = bf2f(dpar[d]);
    float h = 0.f;
    const size_t tokBase = (size_t)b * LSEQ;
    for (int t = 0; t < LSEQ; ++t) {
        const size_t tok = tokBase + t;
        float dl = delta[tok * DI + d];
        float uu = bf2f(ub[tok * DI + d]);
        float Bn = dbc[tok * DBCW + DTR + n];
        float Cn = dbc[tok * DBCW + DTR + NS + n];
        float dA = exp2f(dl * Al2);
        h = fmaf(dA, h, dl * Bn * uu);
        float p = h * Cn;
        p += __shfl_xor(p, 1);
        p += __shfl_xor(p, 2);
        p += __shfl_xor(p, 4);
        p += __shfl_xor(p, 8);
        if (n == 0) {
            float r = bf2f(resb[tok * DI + d]);
            float o = (p + uu * Dd) * silu(r);
            yb[tok * DI + d] = f2bf(o);
        }
    }
}

extern "C" void kernel_launch(void* const* d_in, const int* in_sizes, int n_in,
                              void* d_out, int out_size, void* d_ws, size_t ws_size,
                              hipStream_t stream) {
    char* ws = (char*)d_ws;
    size_t off = 0;
    auto take = [&](size_t bytes) { char* p = ws + off; off = (off + bytes + 255) & ~(size_t)255; return p; };
    int*   flag = (int*)take(4);
    short* canon = (short*)take((size_t)O_TOT * 2);
    short* xn   = (short*)take((size_t)NT * DM * 2);
    short* xinb = (short*)take((size_t)NT * DI * 2);
    short* res  = (short*)take((size_t)NT * DI * 2);
    short* ub   = (short*)take((size_t)NT * DI * 2);
    float* dbc  = (float*)take((size_t)NT * DBCW * 4);
    float* delt = (float*)take((size_t)NT * DI * 4);
    short* yb   = (short*)take((size_t)NT * DI * 2);

    const short* cx    = canon + O_X;
    const short* clnw  = canon + O_LNW;
    const short* clnb  = canon + O_LNB;
    const short* cinw  = canon + O_INW;
    const short* ccw   = canon + O_CW;
    const short* ccb   = canon + O_CB;
    const short* cxpw  = canon + O_XPW;
    const short* cdtw  = canon + O_DTW;
    const short* cdtb  = canon + O_DTB;
    const short* calog = canon + O_ALOG;
    const short* cdpar = canon + O_DPAR;
    const short* coutw = canon + O_OUTW;

    detect_kernel<<<1, 64, 0, stream>>>((const unsigned short*)d_in[0], flag);
    canon_kernel<<<(O_TOT + 255) / 256, 256, 0, stream>>>(
        d_in[0], d_in[1], d_in[2], d_in[3], d_in[4], d_in[5],
        d_in[6], d_in[7], d_in[8], d_in[9], d_in[10], d_in[11], flag, canon);

    ln_kernel<<<NT / 4, 256, 0, stream>>>(cx, clnw, clnb, xn);
    gemm_bt<0><<<dim3(2 * DI / 64, NT / 64), 256, 0, stream>>>(xn, cinw, NT, 2 * DI, DM, nullptr, xinb, res, nullptr);
    conv_kernel<<<NT * DI / 256, 256, 0, stream>>>(xinb, ccw, ccb, ub);
    gemm_bt<1><<<dim3((DBCW + 63) / 64, NT / 64), 256, 0, stream>>>(ub, cxpw, NT, DBCW, DI, dbc, nullptr, nullptr, nullptr);
    dtproj_kernel<<<NT, 256, 0, stream>>>(dbc, cdtw, cdtb, delt);
    scan_kernel<<<NBATCH * (DI / 16), 256, 0, stream>>>(delt, ub, dbc, calog, cdpar, res, yb);
    gemm_bt<2><<<dim3(DM / 64, NT / 64), 256, 0, stream>>>(yb, coutw, NT, DM, DI,
                                                           (float*)d_out, (short*)d_out, nullptr, flag);
}

// Round 4
// 507.014 us; speedup vs baseline: 3.5562x; 3.5562x over previous
//
#include <hip/hip_runtime.h>

#define NT 4096      // B*L tokens
#define DM 768
#define DI 1536
#define LSEQ 2048
#define NBATCH 2
#define DBCW 80      // dt_rank + 2*n_state
#define DTR 48
#define NS 16
#define NC 16        // scan chunks
#define LC 128       // chunk length (LSEQ/NC)

// canonical input segment offsets (elements)
#define O_X    0
#define O_LNW  3145728
#define O_LNB  3146496
#define O_INW  3147264
#define O_CW   5506560
#define O_CB   5512704
#define O_XPW  5514240
#define O_DTW  5637120
#define O_DTB  5710848
#define O_ALOG 5712384
#define O_DPAR 5736960
#define O_OUTW 5738496
#define O_TOT  6918144

typedef __attribute__((ext_vector_type(8))) short short8;
typedef __attribute__((ext_vector_type(4))) float float4v;

__device__ __forceinline__ float bf2f(short s) {
    union { unsigned int u; float f; } c; c.u = ((unsigned int)(unsigned short)s) << 16; return c.f;
}
__device__ __forceinline__ float bflo(unsigned int u) {
    union { unsigned int u; float f; } c; c.u = u << 16; return c.f;
}
__device__ __forceinline__ float bfhi(unsigned int u) {
    union { unsigned int u; float f; } c; c.u = u & 0xffff0000u; return c.f;
}
__device__ __forceinline__ short f2bf(float f) {
    union { unsigned int u; float f; } c; c.f = f;
    unsigned int lsb = (c.u >> 16) & 1u;
    unsigned int r = c.u + 0x7fffu + lsb;
    return (short)(r >> 16);
}
__device__ __forceinline__ float silu(float x) { return x / (1.f + __expf(-x)); }

// ---------------- dtype detection: even-index shorts of x ----------------
__global__ void detect_kernel(const unsigned short* __restrict__ x, int* __restrict__ flag) {
    int lane = threadIdx.x & 63;
    unsigned short s = x[lane * 2];
    int e = (s >> 7) & 0xFF;
    bool plaus = (e >= 100 && e <= 140);
    unsigned long long m = __ballot(plaus);
    if (lane == 0) *flag = (__popcll(m) >= 32) ? 0 : 1;  // 0=bf16, 1=f32
}

// ---------------- canonicalize all inputs into one bf16 buffer ----------------
__global__ __launch_bounds__(256) void canon_kernel(
    const void* s0, const void* s1, const void* s2, const void* s3,
    const void* s4, const void* s5, const void* s6, const void* s7,
    const void* s8, const void* s9, const void* s10, const void* s11,
    const int* __restrict__ flag, short* __restrict__ canon) {
    int i = blockIdx.x * 256 + threadIdx.x;
    if (i >= O_TOT) return;
    const void* src; int j;
    if      (i < O_LNW)  { src = s0;  j = i; }
    else if (i < O_LNB)  { src = s1;  j = i - O_LNW; }
    else if (i < O_INW)  { src = s2;  j = i - O_LNB; }
    else if (i < O_CW)   { src = s3;  j = i - O_INW; }
    else if (i < O_CB)   { src = s4;  j = i - O_CW; }
    else if (i < O_XPW)  { src = s5;  j = i - O_CB; }
    else if (i < O_DTW)  { src = s6;  j = i - O_XPW; }
    else if (i < O_DTB)  { src = s7;  j = i - O_DTW; }
    else if (i < O_ALOG) { src = s8;  j = i - O_DTB; }
    else if (i < O_DPAR) { src = s9;  j = i - O_ALOG; }
    else if (i < O_OUTW) { src = s10; j = i - O_DPAR; }
    else                 { src = s11; j = i - O_OUTW; }
    short v;
    if (*flag) v = f2bf(((const float*)src)[j]);
    else       v = ((const short*)src)[j];
    canon[i] = v;
}

// ---------------- LayerNorm: one wave per token ----------------
__global__ __launch_bounds__(256) void ln_kernel(const short* __restrict__ x,
                                                 const short* __restrict__ w,
                                                 const short* __restrict__ b,
                                                 short* __restrict__ xn) {
    const int wave = threadIdx.x >> 6, lane = threadIdx.x & 63;
    const int token = blockIdx.x * 4 + wave;
    const short* xr = x + (size_t)token * DM;
    short* xo = xn + (size_t)token * DM;
    float vals[12];
    float s = 0.f, s2 = 0.f;
#pragma unroll
    for (int j = 0; j < 6; j++) {
        unsigned int u = *(const unsigned int*)(xr + lane * 2 + j * 128);
        float f0 = bflo(u), f1 = bfhi(u);
        vals[2 * j] = f0; vals[2 * j + 1] = f1;
        s += f0 + f1; s2 += f0 * f0 + f1 * f1;
    }
#pragma unroll
    for (int off = 1; off < 64; off <<= 1) {
        s += __shfl_xor(s, off);
        s2 += __shfl_xor(s2, off);
    }
    const float mu = s * (1.f / DM);
    const float var = s2 * (1.f / DM) - mu * mu;
    const float rs = rsqrtf(var + 1e-5f);
#pragma unroll
    for (int j = 0; j < 6; j++) {
        int e = lane * 2 + j * 128;
        unsigned int uw = *(const unsigned int*)(w + e);
        unsigned int ub = *(const unsigned int*)(b + e);
        float o0 = (vals[2 * j] - mu) * rs * bflo(uw) + bflo(ub);
        float o1 = (vals[2 * j + 1] - mu) * rs * bfhi(uw) + bfhi(ub);
        unsigned int pk = (unsigned int)(unsigned short)f2bf(o0) |
                          ((unsigned int)(unsigned short)f2bf(o1) << 16);
        *(unsigned int*)(xo + e) = pk;
    }
}

// ---------------- Generic bf16 MFMA GEMM: C[m,n] = sum_k A[m,k]*B[n,k] ----------------
template <int MODE>
__global__ __launch_bounds__(256) void gemm_bt(const short* __restrict__ A,
                                               const short* __restrict__ B,
                                               int M, int N, int K,
                                               float* __restrict__ outF,
                                               short* __restrict__ outS,
                                               short* __restrict__ outS2,
                                               const int* __restrict__ oflag) {
    __shared__ short As[64 * 40];
    __shared__ short Bs[64 * 40];
    const int tid = threadIdx.x;
    const int mBase = blockIdx.y * 64;
    const int nBase = blockIdx.x * 64;
    const int lrow = tid >> 2;
    const int lcol = (tid & 3) * 8;
    const int wave = tid >> 6;
    const int lane = tid & 63;
    const int l15 = lane & 15;
    const int quad = lane >> 4;
    const int wm = (wave >> 1) * 32;
    const int wn = (wave & 1) * 32;

    float4v acc[2][2] = {};

    const bool bvalid = (nBase + lrow) < N;
    const short* aptr = A + (size_t)(mBase + lrow) * K + lcol;
    const short* bptr = B + (size_t)(nBase + lrow) * K + lcol;
    const short8 bz = {0, 0, 0, 0, 0, 0, 0, 0};

    for (int k0 = 0; k0 < K; k0 += 32) {
        short8 av = *(const short8*)(aptr + k0);
        short8 bv = bvalid ? *(const short8*)(bptr + k0) : bz;
        __syncthreads();
        *(short8*)&As[lrow * 40 + lcol] = av;
        *(short8*)&Bs[lrow * 40 + lcol] = bv;
        __syncthreads();
        short8 a0 = *(const short8*)&As[(wm + l15) * 40 + quad * 8];
        short8 a1 = *(const short8*)&As[(wm + 16 + l15) * 40 + quad * 8];
        short8 b0 = *(const short8*)&Bs[(wn + l15) * 40 + quad * 8];
        short8 b1 = *(const short8*)&Bs[(wn + 16 + l15) * 40 + quad * 8];
        acc[0][0] = __builtin_amdgcn_mfma_f32_16x16x32_bf16(a0, b0, acc[0][0], 0, 0, 0);
        acc[0][1] = __builtin_amdgcn_mfma_f32_16x16x32_bf16(a0, b1, acc[0][1], 0, 0, 0);
        acc[1][0] = __builtin_amdgcn_mfma_f32_16x16x32_bf16(a1, b0, acc[1][0], 0, 0, 0);
        acc[1][1] = __builtin_amdgcn_mfma_f32_16x16x32_bf16(a1, b1, acc[1][1], 0, 0, 0);
    }

    const bool outf32 = (MODE == 2) ? (*oflag != 0) : false;
#pragma unroll
    for (int i = 0; i < 2; i++)
#pragma unroll
        for (int j = 0; j < 2; j++)
#pragma unroll
            for (int r = 0; r < 4; r++) {
                int m = mBase + wm + i * 16 + quad * 4 + r;
                int n = nBase + wn + j * 16 + l15;
                float v = acc[i][j][r];
                if (MODE == 0) {
                    if (n < DI) outS[(size_t)m * DI + n] = f2bf(v);
                    else outS2[(size_t)m * DI + (n - DI)] = f2bf(v);
                } else if (MODE == 1) {
                    if (n < N) outF[(size_t)m * N + n] = v;
                } else {
                    if (outf32) outF[(size_t)m * N + n] = v;
                    else outS[(size_t)m * N + n] = f2bf(v);
                }
            }
}

// ---------------- depthwise causal conv (taps=4) + SiLU ----------------
__global__ __launch_bounds__(256) void conv_kernel(const short* __restrict__ xin,
                                                   const short* __restrict__ cw,
                                                   const short* __restrict__ cb,
                                                   short* __restrict__ ub) {
    const int idx = blockIdx.x * 256 + threadIdx.x;  // over NT*DI, exact
    const int d = idx % DI;
    const int t = idx / DI;
    const int l = t % LSEQ;
    float s = bf2f(cb[d]);
#pragma unroll
    for (int j = 0; j < 4; j++) {
        int lj = l - 3 + j;
        if (lj >= 0) s += bf2f(xin[(size_t)(t - 3 + j) * DI + d]) * bf2f(cw[d * 4 + j]);
    }
    float u = silu(s);
    ub[idx] = f2bf(u);
}

// ---------------- dt_proj (K=48) + softplus ----------------
__global__ __launch_bounds__(256) void dtproj_kernel(const float* __restrict__ dbc,
                                                     const short* __restrict__ dw,
                                                     const short* __restrict__ db,
                                                     float* __restrict__ delta) {
    const int m = blockIdx.x;
    __shared__ float dts[DTR];
    if (threadIdx.x < DTR) dts[threadIdx.x] = dbc[(size_t)m * DBCW + threadIdx.x];
    __syncthreads();
    for (int d = threadIdx.x; d < DI; d += 256) {
        const short* wr = dw + (size_t)d * DTR;
        float s = bf2f(db[d]);
#pragma unroll
        for (int k = 0; k < DTR; k += 2) {
            unsigned int u = *(const unsigned int*)(wr + k);
            s += dts[k] * bflo(u) + dts[k + 1] * bfhi(u);
        }
        float sp = (s > 20.f) ? s : log1pf(__expf(s));
        delta[(size_t)m * DI + d] = sp;
    }
}

// ---------------- chunked scan pass 1: per-chunk (P = prod a, S = h_end | h_in=0) ----------------
// grid: x = chunk c (NC), y = b*96 + dgrp; wave: d = dgrp*16 + wave*4 + (lane>>4), n = lane&15
__global__ __launch_bounds__(256) void scan_p1(const float* __restrict__ delta,
                                               const short* __restrict__ ub,
                                               const float* __restrict__ dbc,
                                               const short* __restrict__ alog,
                                               float* __restrict__ Pws,
                                               float* __restrict__ Sws) {
    const int wave = threadIdx.x >> 6, lane = threadIdx.x & 63;
    const int n = lane & 15, dsub = lane >> 4;
    const int c = blockIdx.x;
    const int b = blockIdx.y / 96;
    const int dgrp = blockIdx.y % 96;
    const int d = dgrp * 16 + wave * 4 + dsub;
    const float Al2 = -__expf(bf2f(alog[d * NS + n])) * 1.44269504f;
    float P = 1.f, S = 0.f;
    const size_t tok0 = (size_t)b * LSEQ + c * LC;
#pragma unroll 4
    for (int t = 0; t < LC; ++t) {
        const size_t tok = tok0 + t;
        float dl = delta[tok * DI + d];
        float uu = bf2f(ub[tok * DI + d]);
        float Bn = dbc[tok * DBCW + DTR + n];
        float a = exp2f(dl * Al2);
        S = fmaf(a, S, dl * Bn * uu);
        P *= a;
    }
    const size_t o = (((size_t)b * NC + c) * DI + d) * NS + n;
    Pws[o] = P;
    Sws[o] = S;
}

// ---------------- chunk combine: Hin[c] = state entering chunk c ----------------
__global__ __launch_bounds__(256) void scan_mid(const float* __restrict__ Pws,
                                                const float* __restrict__ Sws,
                                                float* __restrict__ Hin) {
    const int i = blockIdx.x * 256 + threadIdx.x;  // over NBATCH*DI*NS
    const int b = i / (DI * NS);
    const int dn = i % (DI * NS);
    float h = 0.f;
#pragma unroll
    for (int c = 0; c < NC; ++c) {
        const size_t o = ((size_t)(b * NC + c) * DI * NS) + dn;
        Hin[o] = h;
        h = Sws[o] + Pws[o] * h;
    }
}

// ---------------- chunked scan pass 2: re-scan chunk from Hin, emit gated y ----------------
__global__ __launch_bounds__(256) void scan_p2(const float* __restrict__ delta,
                                               const short* __restrict__ ub,
                                               const float* __restrict__ dbc,
                                               const short* __restrict__ alog,
                                               const short* __restrict__ dpar,
                                               const short* __restrict__ resb,
                                               const float* __restrict__ Hin,
                                               short* __restrict__ yb) {
    const int wave = threadIdx.x >> 6, lane = threadIdx.x & 63;
    const int n = lane & 15, dsub = lane >> 4;
    const int c = blockIdx.x;
    const int b = blockIdx.y / 96;
    const int dgrp = blockIdx.y % 96;
    const int d = dgrp * 16 + wave * 4 + dsub;
    const float Al2 = -__expf(bf2f(alog[d * NS + n])) * 1.44269504f;
    const float Dd = bf2f(dpar[d]);
    float h = Hin[(((size_t)b * NC + c) * DI + d) * NS + n];
    const size_t tok0 = (size_t)b * LSEQ + c * LC;
#pragma unroll 2
    for (int t = 0; t < LC; ++t) {
        const size_t tok = tok0 + t;
        float dl = delta[tok * DI + d];
        float uu = bf2f(ub[tok * DI + d]);
        float Bn = dbc[tok * DBCW + DTR + n];
        float Cn = dbc[tok * DBCW + DTR + NS + n];
        float a = exp2f(dl * Al2);
        h = fmaf(a, h, dl * Bn * uu);
        float p = h * Cn;
        p += __shfl_xor(p, 1);
        p += __shfl_xor(p, 2);
        p += __shfl_xor(p, 4);
        p += __shfl_xor(p, 8);
        if (n == 0) {
            float r = bf2f(resb[tok * DI + d]);
            float o = (p + uu * Dd) * silu(r);
            yb[tok * DI + d] = f2bf(o);
        }
    }
}

extern "C" void kernel_launch(void* const* d_in, const int* in_sizes, int n_in,
                              void* d_out, int out_size, void* d_ws, size_t ws_size,
                              hipStream_t stream) {
    char* ws = (char*)d_ws;
    size_t off = 0;
    auto take = [&](size_t bytes) { char* p = ws + off; off = (off + bytes + 255) & ~(size_t)255; return p; };
    int*   flag = (int*)take(4);
    short* canon = (short*)take((size_t)O_TOT * 2);
    short* xn   = (short*)take((size_t)NT * DM * 2);
    short* xinb = (short*)take((size_t)NT * DI * 2);
    short* res  = (short*)take((size_t)NT * DI * 2);
    short* ub   = (short*)take((size_t)NT * DI * 2);
    float* dbc  = (float*)take((size_t)NT * DBCW * 4);
    float* delt = (float*)take((size_t)NT * DI * 4);
    short* yb   = (short*)take((size_t)NT * DI * 2);
    float* Pws  = (float*)take((size_t)NBATCH * NC * DI * NS * 4);
    float* Sws  = (float*)take((size_t)NBATCH * NC * DI * NS * 4);
    float* Hin  = (float*)take((size_t)NBATCH * NC * DI * NS * 4);

    const short* cx    = canon + O_X;
    const short* clnw  = canon + O_LNW;
    const short* clnb  = canon + O_LNB;
    const short* cinw  = canon + O_INW;
    const short* ccw   = canon + O_CW;
    const short* ccb   = canon + O_CB;
    const short* cxpw  = canon + O_XPW;
    const short* cdtw  = canon + O_DTW;
    const short* cdtb  = canon + O_DTB;
    const short* calog = canon + O_ALOG;
    const short* cdpar = canon + O_DPAR;
    const short* coutw = canon + O_OUTW;

    detect_kernel<<<1, 64, 0, stream>>>((const unsigned short*)d_in[0], flag);
    canon_kernel<<<(O_TOT + 255) / 256, 256, 0, stream>>>(
        d_in[0], d_in[1], d_in[2], d_in[3], d_in[4], d_in[5],
        d_in[6], d_in[7], d_in[8], d_in[9], d_in[10], d_in[11], flag, canon);

    ln_kernel<<<NT / 4, 256, 0, stream>>>(cx, clnw, clnb, xn);
    gemm_bt<0><<<dim3(2 * DI / 64, NT / 64), 256, 0, stream>>>(xn, cinw, NT, 2 * DI, DM, nullptr, xinb, res, nullptr);
    conv_kernel<<<NT * DI / 256, 256, 0, stream>>>(xinb, ccw, ccb, ub);
    gemm_bt<1><<<dim3((DBCW + 63) / 64, NT / 64), 256, 0, stream>>>(ub, cxpw, NT, DBCW, DI, dbc, nullptr, nullptr, nullptr);
    dtproj_kernel<<<NT, 256, 0, stream>>>(dbc, cdtw, cdtb, delt);

    scan_p1<<<dim3(NC, NBATCH * 96), 256, 0, stream>>>(delt, ub, dbc, calog, Pws, Sws);
    scan_mid<<<NBATCH * DI * NS / 256, 256, 0, stream>>>(Pws, Sws, Hin);
    scan_p2<<<dim3(NC, NBATCH * 96), 256, 0, stream>>>(delt, ub, dbc, calog, cdpar, res, Hin, yb);

    gemm_bt<2><<<dim3(DM / 64, NT / 64), 256, 0, stream>>>(yb, coutw, NT, DM, DI,
                                                           (float*)d_out, (short*)d_out, nullptr, flag);
}

// Round 5
// 375.610 us; speedup vs baseline: 4.8003x; 1.3498x over previous
//
#include <hip/hip_runtime.h>

#define NT 4096      // B*L tokens
#define DM 768
#define DI 1536
#define LSEQ 2048
#define NBATCH 2
#define DBCW 80      // dt_rank + 2*n_state
#define DTR 48
#define NS 16
#define NC 32        // scan chunks
#define LC 64        // chunk length (LSEQ/NC)

// canonical input segment offsets (elements)
#define O_X    0
#define O_LNW  3145728
#define O_LNB  3146496
#define O_INW  3147264
#define O_CW   5506560
#define O_CB   5512704
#define O_XPW  5514240
#define O_DTW  5637120
#define O_DTB  5710848
#define O_ALOG 5712384
#define O_DPAR 5736960
#define O_OUTW 5738496
#define O_TOT  6918144

typedef __attribute__((ext_vector_type(8))) short short8;
typedef __attribute__((ext_vector_type(4))) float float4v;

__device__ __forceinline__ float bf2f(short s) {
    union { unsigned int u; float f; } c; c.u = ((unsigned int)(unsigned short)s) << 16; return c.f;
}
__device__ __forceinline__ float bflo(unsigned int u) {
    union { unsigned int u; float f; } c; c.u = u << 16; return c.f;
}
__device__ __forceinline__ float bfhi(unsigned int u) {
    union { unsigned int u; float f; } c; c.u = u & 0xffff0000u; return c.f;
}
__device__ __forceinline__ short f2bf(float f) {
    union { unsigned int u; float f; } c; c.f = f;
    unsigned int lsb = (c.u >> 16) & 1u;
    unsigned int r = c.u + 0x7fffu + lsb;
    return (short)(r >> 16);
}
__device__ __forceinline__ float silu(float x) { return x / (1.f + __expf(-x)); }

// ---------------- dtype detection: even-index shorts of x ----------------
__global__ void detect_kernel(const unsigned short* __restrict__ x, int* __restrict__ flag) {
    int lane = threadIdx.x & 63;
    unsigned short s = x[lane * 2];
    int e = (s >> 7) & 0xFF;
    bool plaus = (e >= 100 && e <= 140);
    unsigned long long m = __ballot(plaus);
    if (lane == 0) *flag = (__popcll(m) >= 32) ? 0 : 1;  // 0=bf16, 1=f32
}

// ---------------- canonicalize all inputs into one bf16 buffer ----------------
__global__ __launch_bounds__(256) void canon_kernel(
    const void* s0, const void* s1, const void* s2, const void* s3,
    const void* s4, const void* s5, const void* s6, const void* s7,
    const void* s8, const void* s9, const void* s10, const void* s11,
    const int* __restrict__ flag, short* __restrict__ canon) {
    int i = blockIdx.x * 256 + threadIdx.x;
    if (i >= O_TOT) return;
    const void* src; int j;
    if      (i < O_LNW)  { src = s0;  j = i; }
    else if (i < O_LNB)  { src = s1;  j = i - O_LNW; }
    else if (i < O_INW)  { src = s2;  j = i - O_LNB; }
    else if (i < O_CW)   { src = s3;  j = i - O_INW; }
    else if (i < O_CB)   { src = s4;  j = i - O_CW; }
    else if (i < O_XPW)  { src = s5;  j = i - O_CB; }
    else if (i < O_DTW)  { src = s6;  j = i - O_XPW; }
    else if (i < O_DTB)  { src = s7;  j = i - O_DTW; }
    else if (i < O_ALOG) { src = s8;  j = i - O_DTB; }
    else if (i < O_DPAR) { src = s9;  j = i - O_ALOG; }
    else if (i < O_OUTW) { src = s10; j = i - O_DPAR; }
    else                 { src = s11; j = i - O_OUTW; }
    short v;
    if (*flag) v = f2bf(((const float*)src)[j]);
    else       v = ((const short*)src)[j];
    canon[i] = v;
}

// ---------------- LayerNorm: one wave per token ----------------
__global__ __launch_bounds__(256) void ln_kernel(const short* __restrict__ x,
                                                 const short* __restrict__ w,
                                                 const short* __restrict__ b,
                                                 short* __restrict__ xn) {
    const int wave = threadIdx.x >> 6, lane = threadIdx.x & 63;
    const int token = blockIdx.x * 4 + wave;
    const short* xr = x + (size_t)token * DM;
    short* xo = xn + (size_t)token * DM;
    float vals[12];
    float s = 0.f, s2 = 0.f;
#pragma unroll
    for (int j = 0; j < 6; j++) {
        unsigned int u = *(const unsigned int*)(xr + lane * 2 + j * 128);
        float f0 = bflo(u), f1 = bfhi(u);
        vals[2 * j] = f0; vals[2 * j + 1] = f1;
        s += f0 + f1; s2 += f0 * f0 + f1 * f1;
    }
#pragma unroll
    for (int off = 1; off < 64; off <<= 1) {
        s += __shfl_xor(s, off);
        s2 += __shfl_xor(s2, off);
    }
    const float mu = s * (1.f / DM);
    const float var = s2 * (1.f / DM) - mu * mu;
    const float rs = rsqrtf(var + 1e-5f);
#pragma unroll
    for (int j = 0; j < 6; j++) {
        int e = lane * 2 + j * 128;
        unsigned int uw = *(const unsigned int*)(w + e);
        unsigned int ub = *(const unsigned int*)(b + e);
        float o0 = (vals[2 * j] - mu) * rs * bflo(uw) + bflo(ub);
        float o1 = (vals[2 * j + 1] - mu) * rs * bfhi(uw) + bfhi(ub);
        unsigned int pk = (unsigned int)(unsigned short)f2bf(o0) |
                          ((unsigned int)(unsigned short)f2bf(o1) << 16);
        *(unsigned int*)(xo + e) = pk;
    }
}

// ---------------- Generic bf16 MFMA GEMM: C[m,n] = sum_k A[m,k]*B[n,k] ----------------
template <int MODE>
__global__ __launch_bounds__(256) void gemm_bt(const short* __restrict__ A,
                                               const short* __restrict__ B,
                                               int M, int N, int K,
                                               float* __restrict__ outF,
                                               short* __restrict__ outS,
                                               short* __restrict__ outS2,
                                               const int* __restrict__ oflag) {
    __shared__ short As[64 * 40];
    __shared__ short Bs[64 * 40];
    const int tid = threadIdx.x;
    const int mBase = blockIdx.y * 64;
    const int nBase = blockIdx.x * 64;
    const int lrow = tid >> 2;
    const int lcol = (tid & 3) * 8;
    const int wave = tid >> 6;
    const int lane = tid & 63;
    const int l15 = lane & 15;
    const int quad = lane >> 4;
    const int wm = (wave >> 1) * 32;
    const int wn = (wave & 1) * 32;

    float4v acc[2][2] = {};

    const bool bvalid = (nBase + lrow) < N;
    const short* aptr = A + (size_t)(mBase + lrow) * K + lcol;
    const short* bptr = B + (size_t)(nBase + lrow) * K + lcol;
    const short8 bz = {0, 0, 0, 0, 0, 0, 0, 0};

    for (int k0 = 0; k0 < K; k0 += 32) {
        short8 av = *(const short8*)(aptr + k0);
        short8 bv = bvalid ? *(const short8*)(bptr + k0) : bz;
        __syncthreads();
        *(short8*)&As[lrow * 40 + lcol] = av;
        *(short8*)&Bs[lrow * 40 + lcol] = bv;
        __syncthreads();
        short8 a0 = *(const short8*)&As[(wm + l15) * 40 + quad * 8];
        short8 a1 = *(const short8*)&As[(wm + 16 + l15) * 40 + quad * 8];
        short8 b0 = *(const short8*)&Bs[(wn + l15) * 40 + quad * 8];
        short8 b1 = *(const short8*)&Bs[(wn + 16 + l15) * 40 + quad * 8];
        acc[0][0] = __builtin_amdgcn_mfma_f32_16x16x32_bf16(a0, b0, acc[0][0], 0, 0, 0);
        acc[0][1] = __builtin_amdgcn_mfma_f32_16x16x32_bf16(a0, b1, acc[0][1], 0, 0, 0);
        acc[1][0] = __builtin_amdgcn_mfma_f32_16x16x32_bf16(a1, b0, acc[1][0], 0, 0, 0);
        acc[1][1] = __builtin_amdgcn_mfma_f32_16x16x32_bf16(a1, b1, acc[1][1], 0, 0, 0);
    }

    const bool outf32 = (MODE == 2) ? (*oflag != 0) : false;
#pragma unroll
    for (int i = 0; i < 2; i++)
#pragma unroll
        for (int j = 0; j < 2; j++)
#pragma unroll
            for (int r = 0; r < 4; r++) {
                int m = mBase + wm + i * 16 + quad * 4 + r;
                int n = nBase + wn + j * 16 + l15;
                float v = acc[i][j][r];
                if (MODE == 0) {
                    if (n < DI) outS[(size_t)m * DI + n] = f2bf(v);
                    else outS2[(size_t)m * DI + (n - DI)] = f2bf(v);
                } else if (MODE == 1) {
                    if (n < N) outF[(size_t)m * N + n] = v;
                } else {
                    if (outf32) outF[(size_t)m * N + n] = v;
                    else outS[(size_t)m * N + n] = f2bf(v);
                }
            }
}

// ---------------- depthwise causal conv (taps=4) + SiLU ----------------
__global__ __launch_bounds__(256) void conv_kernel(const short* __restrict__ xin,
                                                   const short* __restrict__ cw,
                                                   const short* __restrict__ cb,
                                                   short* __restrict__ ub) {
    const int idx = blockIdx.x * 256 + threadIdx.x;  // over NT*DI, exact
    const int d = idx % DI;
    const int t = idx / DI;
    const int l = t % LSEQ;
    float s = bf2f(cb[d]);
#pragma unroll
    for (int j = 0; j < 4; j++) {
        int lj = l - 3 + j;
        if (lj >= 0) s += bf2f(xin[(size_t)(t - 3 + j) * DI + d]) * bf2f(cw[d * 4 + j]);
    }
    float u = silu(s);
    ub[idx] = f2bf(u);
}

// ---------------- dt_proj (K=48) + softplus ----------------
__global__ __launch_bounds__(256) void dtproj_kernel(const float* __restrict__ dbc,
                                                     const short* __restrict__ dw,
                                                     const short* __restrict__ db,
                                                     float* __restrict__ delta) {
    const int m = blockIdx.x;
    __shared__ float dts[DTR];
    if (threadIdx.x < DTR) dts[threadIdx.x] = dbc[(size_t)m * DBCW + threadIdx.x];
    __syncthreads();
    for (int d = threadIdx.x; d < DI; d += 256) {
        const short* wr = dw + (size_t)d * DTR;
        float s = bf2f(db[d]);
#pragma unroll
        for (int k = 0; k < DTR; k += 2) {
            unsigned int u = *(const unsigned int*)(wr + k);
            s += dts[k] * bflo(u) + dts[k + 1] * bfhi(u);
        }
        float sp = (s > 20.f) ? s : log1pf(__expf(s));
        delta[(size_t)m * DI + d] = sp;
    }
}

// ---------------- scan pass 1 (lane-owns-d): chunk summary S (h_end | h_in=0), P via log-space ----
// grid: x = chunk c, y = b*6 + dblk; lane d = dblk*256 + tid. h[16] in regs, B wave-uniform.
__global__ __launch_bounds__(256) void scan_p1(const float* __restrict__ delta,
                                               const short* __restrict__ ub,
                                               const float* __restrict__ dbc,
                                               const short* __restrict__ alog,
                                               float* __restrict__ Pws,
                                               float* __restrict__ Sws) {
    const int c = blockIdx.x;
    const int b = blockIdx.y / 6;
    const int dblk = blockIdx.y % 6;
    const int d = dblk * 256 + threadIdx.x;

    float Al2[NS];
    {
        short8 a0 = *(const short8*)(alog + (size_t)d * NS);
        short8 a1 = *(const short8*)(alog + (size_t)d * NS + 8);
#pragma unroll
        for (int n = 0; n < 8; n++) {
            Al2[n]     = -__expf(bf2f(a0[n])) * 1.44269504f;
            Al2[n + 8] = -__expf(bf2f(a1[n])) * 1.44269504f;
        }
    }
    float S[NS];
#pragma unroll
    for (int n = 0; n < NS; n++) S[n] = 0.f;
    float sdl = 0.f;
    const size_t tok0 = (size_t)b * LSEQ + (size_t)c * LC;
#pragma unroll 2
    for (int t = 0; t < LC; ++t) {
        const size_t tok = tok0 + t;
        float dl = delta[tok * DI + d];
        float uu = bf2f(ub[tok * DI + d]);
        const float* bp = dbc + tok * DBCW + DTR;
        float Bq[NS];
        *(float4v*)&Bq[0]  = *(const float4v*)(bp);
        *(float4v*)&Bq[4]  = *(const float4v*)(bp + 4);
        *(float4v*)&Bq[8]  = *(const float4v*)(bp + 8);
        *(float4v*)&Bq[12] = *(const float4v*)(bp + 12);
        float du = dl * uu;
        sdl += dl;
#pragma unroll
        for (int n = 0; n < NS; n++) {
            float a = exp2f(dl * Al2[n]);
            S[n] = fmaf(a, S[n], du * Bq[n]);
        }
    }
    const size_t o = (((size_t)b * NC + c) * DI + d) * NS;
#pragma unroll
    for (int n = 0; n < NS; n += 4)
        *(float4v*)(Sws + o + n) = *(const float4v*)&S[n];
    float P[NS];
#pragma unroll
    for (int n = 0; n < NS; n++) P[n] = exp2f(Al2[n] * sdl);
#pragma unroll
    for (int n = 0; n < NS; n += 4)
        *(float4v*)(Pws + o + n) = *(const float4v*)&P[n];
}

// ---------------- chunk combine: Hin[c] = state entering chunk c ----------------
__global__ __launch_bounds__(256) void scan_mid(const float* __restrict__ Pws,
                                                const float* __restrict__ Sws,
                                                float* __restrict__ Hin) {
    const int i = blockIdx.x * 256 + threadIdx.x;  // over NBATCH*DI*NS
    const int b = i / (DI * NS);
    const int dn = i % (DI * NS);
    float h = 0.f;
#pragma unroll 4
    for (int c = 0; c < NC; ++c) {
        const size_t o = ((size_t)(b * NC + c) * DI * NS) + dn;
        Hin[o] = h;
        h = Sws[o] + Pws[o] * h;
    }
}

// ---------------- scan pass 2 (lane-owns-d): re-scan from Hin, emit gated y ----------------
__global__ __launch_bounds__(256) void scan_p2(const float* __restrict__ delta,
                                               const short* __restrict__ ub,
                                               const float* __restrict__ dbc,
                                               const short* __restrict__ alog,
                                               const short* __restrict__ dpar,
                                               const short* __restrict__ resb,
                                               const float* __restrict__ Hin,
                                               short* __restrict__ yb) {
    const int c = blockIdx.x;
    const int b = blockIdx.y / 6;
    const int dblk = blockIdx.y % 6;
    const int d = dblk * 256 + threadIdx.x;

    float Al2[NS];
    {
        short8 a0 = *(const short8*)(alog + (size_t)d * NS);
        short8 a1 = *(const short8*)(alog + (size_t)d * NS + 8);
#pragma unroll
        for (int n = 0; n < 8; n++) {
            Al2[n]     = -__expf(bf2f(a0[n])) * 1.44269504f;
            Al2[n + 8] = -__expf(bf2f(a1[n])) * 1.44269504f;
        }
    }
    const float Dd = bf2f(dpar[d]);
    float h[NS];
    {
        const size_t o = (((size_t)b * NC + c) * DI + d) * NS;
#pragma unroll
        for (int n = 0; n < NS; n += 4)
            *(float4v*)&h[n] = *(const float4v*)(Hin + o + n);
    }
    const size_t tok0 = (size_t)b * LSEQ + (size_t)c * LC;
#pragma unroll 2
    for (int t = 0; t < LC; ++t) {
        const size_t tok = tok0 + t;
        float dl = delta[tok * DI + d];
        float uu = bf2f(ub[tok * DI + d]);
        float rr = bf2f(resb[tok * DI + d]);
        const float* bp = dbc + tok * DBCW + DTR;
        float Bq[NS], Cq[NS];
        *(float4v*)&Bq[0]  = *(const float4v*)(bp);
        *(float4v*)&Bq[4]  = *(const float4v*)(bp + 4);
        *(float4v*)&Bq[8]  = *(const float4v*)(bp + 8);
        *(float4v*)&Bq[12] = *(const float4v*)(bp + 12);
        *(float4v*)&Cq[0]  = *(const float4v*)(bp + 16);
        *(float4v*)&Cq[4]  = *(const float4v*)(bp + 20);
        *(float4v*)&Cq[8]  = *(const float4v*)(bp + 24);
        *(float4v*)&Cq[12] = *(const float4v*)(bp + 28);
        float du = dl * uu;
        float y0 = 0.f, y1 = 0.f, y2 = 0.f, y3 = 0.f;
#pragma unroll
        for (int n = 0; n < NS; n += 4) {
            float a0 = exp2f(dl * Al2[n]);
            float a1 = exp2f(dl * Al2[n + 1]);
            float a2 = exp2f(dl * Al2[n + 2]);
            float a3 = exp2f(dl * Al2[n + 3]);
            h[n]     = fmaf(a0, h[n],     du * Bq[n]);
            h[n + 1] = fmaf(a1, h[n + 1], du * Bq[n + 1]);
            h[n + 2] = fmaf(a2, h[n + 2], du * Bq[n + 2]);
            h[n + 3] = fmaf(a3, h[n + 3], du * Bq[n + 3]);
            y0 = fmaf(h[n],     Cq[n],     y0);
            y1 = fmaf(h[n + 1], Cq[n + 1], y1);
            y2 = fmaf(h[n + 2], Cq[n + 2], y2);
            y3 = fmaf(h[n + 3], Cq[n + 3], y3);
        }
        float y = (y0 + y1) + (y2 + y3) + uu * Dd;
        yb[tok * DI + d] = f2bf(y * silu(rr));
    }
}

extern "C" void kernel_launch(void* const* d_in, const int* in_sizes, int n_in,
                              void* d_out, int out_size, void* d_ws, size_t ws_size,
                              hipStream_t stream) {
    char* ws = (char*)d_ws;
    size_t off = 0;
    auto take = [&](size_t bytes) { char* p = ws + off; off = (off + bytes + 255) & ~(size_t)255; return p; };
    int*   flag = (int*)take(4);
    short* canon = (short*)take((size_t)O_TOT * 2);
    short* xn   = (short*)take((size_t)NT * DM * 2);    // dead after gemm<0>; reused as Pws
    short* xinb = (short*)take((size_t)NT * DI * 2);    // dead after conv; reused as Sws
    short* res  = (short*)take((size_t)NT * DI * 2);
    short* ub   = (short*)take((size_t)NT * DI * 2);
    float* dbc  = (float*)take((size_t)NT * DBCW * 4);
    float* delt = (float*)take((size_t)NT * DI * 4);
    short* yb   = (short*)take((size_t)NT * DI * 2);
    float* Hin  = (float*)take((size_t)NBATCH * NC * DI * NS * 4);
    // aliases (lifetimes disjoint): Pws needs 2*32*1536*16*4 = 6291456 B == NT*DM*2; Sws fits in xinb
    float* Pws = (float*)xn;
    float* Sws = (float*)xinb;

    const short* cx    = canon + O_X;
    const short* clnw  = canon + O_LNW;
    const short* clnb  = canon + O_LNB;
    const short* cinw  = canon + O_INW;
    const short* ccw   = canon + O_CW;
    const short* ccb   = canon + O_CB;
    const short* cxpw  = canon + O_XPW;
    const short* cdtw  = canon + O_DTW;
    const short* cdtb  = canon + O_DTB;
    const short* calog = canon + O_ALOG;
    const short* cdpar = canon + O_DPAR;
    const short* coutw = canon + O_OUTW;

    detect_kernel<<<1, 64, 0, stream>>>((const unsigned short*)d_in[0], flag);
    canon_kernel<<<(O_TOT + 255) / 256, 256, 0, stream>>>(
        d_in[0], d_in[1], d_in[2], d_in[3], d_in[4], d_in[5],
        d_in[6], d_in[7], d_in[8], d_in[9], d_in[10], d_in[11], flag, canon);

    ln_kernel<<<NT / 4, 256, 0, stream>>>(cx, clnw, clnb, xn);
    gemm_bt<0><<<dim3(2 * DI / 64, NT / 64), 256, 0, stream>>>(xn, cinw, NT, 2 * DI, DM, nullptr, xinb, res, nullptr);
    conv_kernel<<<NT * DI / 256, 256, 0, stream>>>(xinb, ccw, ccb, ub);
    gemm_bt<1><<<dim3((DBCW + 63) / 64, NT / 64), 256, 0, stream>>>(ub, cxpw, NT, DBCW, DI, dbc, nullptr, nullptr, nullptr);
    dtproj_kernel<<<NT, 256, 0, stream>>>(dbc, cdtw, cdtb, delt);

    scan_p1<<<dim3(NC, NBATCH * 6), 256, 0, stream>>>(delt, ub, dbc, calog, Pws, Sws);
    scan_mid<<<NBATCH * DI * NS / 256, 256, 0, stream>>>(Pws, Sws, Hin);
    scan_p2<<<dim3(NC, NBATCH * 6), 256, 0, stream>>>(delt, ub, dbc, calog, cdpar, res, Hin, yb);

    gemm_bt<2><<<dim3(DM / 64, NT / 64), 256, 0, stream>>>(yb, coutw, NT, DM, DI,
                                                           (float*)d_out, (short*)d_out, nullptr, flag);
}

// Round 6
// 350.811 us; speedup vs baseline: 5.1396x; 1.0707x over previous
//
#include <hip/hip_runtime.h>

#define NT 4096      // B*L tokens
#define DM 768
#define DI 1536
#define LSEQ 2048
#define NBATCH 2
#define DBCW 80      // dt_rank + 2*n_state
#define DTR 48
#define NS 16
#define NC 64        // scan chunks
#define LC 32        // chunk length (LSEQ/NC)

// canonical input segment offsets (elements)
#define O_X    0
#define O_LNW  3145728
#define O_LNB  3146496
#define O_INW  3147264
#define O_CW   5506560
#define O_CB   5512704
#define O_XPW  5514240
#define O_DTW  5637120
#define O_DTB  5710848
#define O_ALOG 5712384
#define O_DPAR 5736960
#define O_OUTW 5738496
#define O_TOT  6918144

typedef __attribute__((ext_vector_type(8))) short short8;
typedef __attribute__((ext_vector_type(4))) float float4v;

__device__ __forceinline__ float bf2f(short s) {
    union { unsigned int u; float f; } c; c.u = ((unsigned int)(unsigned short)s) << 16; return c.f;
}
__device__ __forceinline__ float bflo(unsigned int u) {
    union { unsigned int u; float f; } c; c.u = u << 16; return c.f;
}
__device__ __forceinline__ float bfhi(unsigned int u) {
    union { unsigned int u; float f; } c; c.u = u & 0xffff0000u; return c.f;
}
__device__ __forceinline__ short f2bf(float f) {
    union { unsigned int u; float f; } c; c.f = f;
    unsigned int lsb = (c.u >> 16) & 1u;
    unsigned int r = c.u + 0x7fffu + lsb;
    return (short)(r >> 16);
}
__device__ __forceinline__ float silu(float x) { return x / (1.f + __expf(-x)); }

// ---------------- dtype detection: even-index shorts of x ----------------
__global__ void detect_kernel(const unsigned short* __restrict__ x, int* __restrict__ flag) {
    int lane = threadIdx.x & 63;
    unsigned short s = x[lane * 2];
    int e = (s >> 7) & 0xFF;
    bool plaus = (e >= 100 && e <= 140);
    unsigned long long m = __ballot(plaus);
    if (lane == 0) *flag = (__popcll(m) >= 32) ? 0 : 1;  // 0=bf16, 1=f32
}

// ---------------- canonicalize all inputs into one bf16 buffer ----------------
__global__ __launch_bounds__(256) void canon_kernel(
    const void* s0, const void* s1, const void* s2, const void* s3,
    const void* s4, const void* s5, const void* s6, const void* s7,
    const void* s8, const void* s9, const void* s10, const void* s11,
    const int* __restrict__ flag, short* __restrict__ canon) {
    int i = blockIdx.x * 256 + threadIdx.x;
    if (i >= O_TOT) return;
    const void* src; int j;
    if      (i < O_LNW)  { src = s0;  j = i; }
    else if (i < O_LNB)  { src = s1;  j = i - O_LNW; }
    else if (i < O_INW)  { src = s2;  j = i - O_LNB; }
    else if (i < O_CW)   { src = s3;  j = i - O_INW; }
    else if (i < O_CB)   { src = s4;  j = i - O_CW; }
    else if (i < O_XPW)  { src = s5;  j = i - O_CB; }
    else if (i < O_DTW)  { src = s6;  j = i - O_XPW; }
    else if (i < O_DTB)  { src = s7;  j = i - O_DTW; }
    else if (i < O_ALOG) { src = s8;  j = i - O_DTB; }
    else if (i < O_DPAR) { src = s9;  j = i - O_ALOG; }
    else if (i < O_OUTW) { src = s10; j = i - O_DPAR; }
    else                 { src = s11; j = i - O_OUTW; }
    short v;
    if (*flag) v = f2bf(((const float*)src)[j]);
    else       v = ((const short*)src)[j];
    canon[i] = v;
}

// ---------------- LayerNorm: one wave per token ----------------
__global__ __launch_bounds__(256) void ln_kernel(const short* __restrict__ x,
                                                 const short* __restrict__ w,
                                                 const short* __restrict__ b,
                                                 short* __restrict__ xn) {
    const int wave = threadIdx.x >> 6, lane = threadIdx.x & 63;
    const int token = blockIdx.x * 4 + wave;
    const short* xr = x + (size_t)token * DM;
    short* xo = xn + (size_t)token * DM;
    float vals[12];
    float s = 0.f, s2 = 0.f;
#pragma unroll
    for (int j = 0; j < 6; j++) {
        unsigned int u = *(const unsigned int*)(xr + lane * 2 + j * 128);
        float f0 = bflo(u), f1 = bfhi(u);
        vals[2 * j] = f0; vals[2 * j + 1] = f1;
        s += f0 + f1; s2 += f0 * f0 + f1 * f1;
    }
#pragma unroll
    for (int off = 1; off < 64; off <<= 1) {
        s += __shfl_xor(s, off);
        s2 += __shfl_xor(s2, off);
    }
    const float mu = s * (1.f / DM);
    const float var = s2 * (1.f / DM) - mu * mu;
    const float rs = rsqrtf(var + 1e-5f);
#pragma unroll
    for (int j = 0; j < 6; j++) {
        int e = lane * 2 + j * 128;
        unsigned int uw = *(const unsigned int*)(w + e);
        unsigned int ub = *(const unsigned int*)(b + e);
        float o0 = (vals[2 * j] - mu) * rs * bflo(uw) + bflo(ub);
        float o1 = (vals[2 * j + 1] - mu) * rs * bfhi(uw) + bfhi(ub);
        unsigned int pk = (unsigned int)(unsigned short)f2bf(o0) |
                          ((unsigned int)(unsigned short)f2bf(o1) << 16);
        *(unsigned int*)(xo + e) = pk;
    }
}

// ---------------- 128x128 bf16 MFMA GEMM: C[m,n] = sum_k A[m,k]*B[n,k] ----------------
// MODE 0: split epilogue (in_proj): n<DI -> outS bf16 (stride DI), else outS2 (stride DI)
// MODE 2: out_proj: *oflag ? f32 outF : bf16 outS, stride DM
template <int MODE>
__global__ __launch_bounds__(256) void gemm128(const short* __restrict__ A,
                                               const short* __restrict__ B,
                                               int K,
                                               float* __restrict__ outF,
                                               short* __restrict__ outS,
                                               short* __restrict__ outS2,
                                               const int* __restrict__ oflag) {
    __shared__ short As[128 * 40];
    __shared__ short Bs[128 * 40];
    const int tid = threadIdx.x;
    const int wave = tid >> 6, lane = tid & 63;
    const int mBase = blockIdx.y * 128, nBase = blockIdx.x * 128;
    const int l15 = lane & 15, quad = lane >> 4;
    const int wm = (wave >> 1) * 64;
    const int wn = (wave & 1) * 64;
    const int srow = tid >> 2;          // 0..63
    const int scol = (tid & 3) * 8;     // 0,8,16,24
    const short* aP = A + (size_t)(mBase + srow) * K + scol;
    const short* bP = B + (size_t)(nBase + srow) * K + scol;
    const size_t half = (size_t)64 * K;

    float4v acc[4][4] = {};

    for (int k0 = 0; k0 < K; k0 += 32) {
        short8 a0 = *(const short8*)(aP + k0);
        short8 a1 = *(const short8*)(aP + half + k0);
        short8 b0 = *(const short8*)(bP + k0);
        short8 b1 = *(const short8*)(bP + half + k0);
        __syncthreads();
        *(short8*)&As[srow * 40 + scol] = a0;
        *(short8*)&As[(srow + 64) * 40 + scol] = a1;
        *(short8*)&Bs[srow * 40 + scol] = b0;
        *(short8*)&Bs[(srow + 64) * 40 + scol] = b1;
        __syncthreads();
        short8 af[4], bf[4];
#pragma unroll
        for (int i = 0; i < 4; i++) {
            af[i] = *(const short8*)&As[(wm + i * 16 + l15) * 40 + quad * 8];
            bf[i] = *(const short8*)&Bs[(wn + i * 16 + l15) * 40 + quad * 8];
        }
#pragma unroll
        for (int i = 0; i < 4; i++)
#pragma unroll
            for (int j = 0; j < 4; j++)
                acc[i][j] = __builtin_amdgcn_mfma_f32_16x16x32_bf16(af[i], bf[j], acc[i][j], 0, 0, 0);
    }

    const bool outf32 = (MODE == 2) ? (*oflag != 0) : false;
#pragma unroll
    for (int i = 0; i < 4; i++)
#pragma unroll
        for (int j = 0; j < 4; j++)
#pragma unroll
            for (int r = 0; r < 4; r++) {
                int m = mBase + wm + i * 16 + quad * 4 + r;
                int n = nBase + wn + j * 16 + l15;
                float v = acc[i][j][r];
                if (MODE == 0) {
                    if (n < DI) outS[(size_t)m * DI + n] = f2bf(v);
                    else outS2[(size_t)m * DI + (n - DI)] = f2bf(v);
                } else {
                    if (outf32) outF[(size_t)m * DM + n] = v;
                    else outS[(size_t)m * DM + n] = f2bf(v);
                }
            }
}

// ---------------- 64-tile GEMM for x_proj (N=80) ----------------
__global__ __launch_bounds__(256) void gemm_small(const short* __restrict__ A,
                                                  const short* __restrict__ B,
                                                  int N, int K,
                                                  float* __restrict__ outF) {
    __shared__ short As[64 * 40];
    __shared__ short Bs[64 * 40];
    const int tid = threadIdx.x;
    const int mBase = blockIdx.y * 64;
    const int nBase = blockIdx.x * 64;
    const int lrow = tid >> 2;
    const int lcol = (tid & 3) * 8;
    const int wave = tid >> 6;
    const int lane = tid & 63;
    const int l15 = lane & 15;
    const int quad = lane >> 4;
    const int wm = (wave >> 1) * 32;
    const int wn = (wave & 1) * 32;

    float4v acc[2][2] = {};

    const bool bvalid = (nBase + lrow) < N;
    const short* aptr = A + (size_t)(mBase + lrow) * K + lcol;
    const short* bptr = B + (size_t)(nBase + lrow) * K + lcol;
    const short8 bz = {0, 0, 0, 0, 0, 0, 0, 0};

    for (int k0 = 0; k0 < K; k0 += 32) {
        short8 av = *(const short8*)(aptr + k0);
        short8 bv = bvalid ? *(const short8*)(bptr + k0) : bz;
        __syncthreads();
        *(short8*)&As[lrow * 40 + lcol] = av;
        *(short8*)&Bs[lrow * 40 + lcol] = bv;
        __syncthreads();
        short8 a0 = *(const short8*)&As[(wm + l15) * 40 + quad * 8];
        short8 a1 = *(const short8*)&As[(wm + 16 + l15) * 40 + quad * 8];
        short8 b0 = *(const short8*)&Bs[(wn + l15) * 40 + quad * 8];
        short8 b1 = *(const short8*)&Bs[(wn + 16 + l15) * 40 + quad * 8];
        acc[0][0] = __builtin_amdgcn_mfma_f32_16x16x32_bf16(a0, b0, acc[0][0], 0, 0, 0);
        acc[0][1] = __builtin_amdgcn_mfma_f32_16x16x32_bf16(a0, b1, acc[0][1], 0, 0, 0);
        acc[1][0] = __builtin_amdgcn_mfma_f32_16x16x32_bf16(a1, b0, acc[1][0], 0, 0, 0);
        acc[1][1] = __builtin_amdgcn_mfma_f32_16x16x32_bf16(a1, b1, acc[1][1], 0, 0, 0);
    }

#pragma unroll
    for (int i = 0; i < 2; i++)
#pragma unroll
        for (int j = 0; j < 2; j++)
#pragma unroll
            for (int r = 0; r < 4; r++) {
                int m = mBase + wm + i * 16 + quad * 4 + r;
                int n = nBase + wn + j * 16 + l15;
                if (n < N) outF[(size_t)m * N + n] = acc[i][j][r];
            }
}

// ---------------- depthwise causal conv (taps=4) + SiLU ----------------
__global__ __launch_bounds__(256) void conv_kernel(const short* __restrict__ xin,
                                                   const short* __restrict__ cw,
                                                   const short* __restrict__ cb,
                                                   short* __restrict__ ub) {
    const int idx = blockIdx.x * 256 + threadIdx.x;  // over NT*DI, exact
    const int d = idx % DI;
    const int t = idx / DI;
    const int l = t % LSEQ;
    float s = bf2f(cb[d]);
#pragma unroll
    for (int j = 0; j < 4; j++) {
        int lj = l - 3 + j;
        if (lj >= 0) s += bf2f(xin[(size_t)(t - 3 + j) * DI + d]) * bf2f(cw[d * 4 + j]);
    }
    float u = silu(s);
    ub[idx] = f2bf(u);
}

// ---------------- dt_proj (K=48) + softplus ----------------
__global__ __launch_bounds__(256) void dtproj_kernel(const float* __restrict__ dbc,
                                                     const short* __restrict__ dw,
                                                     const short* __restrict__ db,
                                                     float* __restrict__ delta) {
    const int m = blockIdx.x;
    __shared__ float dts[DTR];
    if (threadIdx.x < DTR) dts[threadIdx.x] = dbc[(size_t)m * DBCW + threadIdx.x];
    __syncthreads();
    for (int d = threadIdx.x; d < DI; d += 256) {
        const short* wr = dw + (size_t)d * DTR;
        float s = bf2f(db[d]);
#pragma unroll
        for (int k = 0; k < DTR; k += 2) {
            unsigned int u = *(const unsigned int*)(wr + k);
            s += dts[k] * bflo(u) + dts[k + 1] * bfhi(u);
        }
        float sp = (s > 20.f) ? s : log1pf(__expf(s));
        delta[(size_t)m * DI + d] = sp;
    }
}

// ---------------- scan pass 1 (lane-owns-d): chunk summary S, P via log-space ----------------
__global__ __launch_bounds__(256) void scan_p1(const float* __restrict__ delta,
                                               const short* __restrict__ ub,
                                               const float* __restrict__ dbc,
                                               const short* __restrict__ alog,
                                               float* __restrict__ Pws,
                                               float* __restrict__ Sws) {
    const int c = blockIdx.x;
    const int b = blockIdx.y / 6;
    const int dblk = blockIdx.y % 6;
    const int d = dblk * 256 + threadIdx.x;

    float Al2[NS];
    {
        short8 a0 = *(const short8*)(alog + (size_t)d * NS);
        short8 a1 = *(const short8*)(alog + (size_t)d * NS + 8);
#pragma unroll
        for (int n = 0; n < 8; n++) {
            Al2[n]     = -__expf(bf2f(a0[n])) * 1.44269504f;
            Al2[n + 8] = -__expf(bf2f(a1[n])) * 1.44269504f;
        }
    }
    float S[NS];
#pragma unroll
    for (int n = 0; n < NS; n++) S[n] = 0.f;
    float sdl = 0.f;
    const size_t tok0 = (size_t)b * LSEQ + (size_t)c * LC;
#pragma unroll 2
    for (int t = 0; t < LC; ++t) {
        const size_t tok = tok0 + t;
        float dl = delta[tok * DI + d];
        float uu = bf2f(ub[tok * DI + d]);
        const float* bp = dbc + tok * DBCW + DTR;
        float Bq[NS];
        *(float4v*)&Bq[0]  = *(const float4v*)(bp);
        *(float4v*)&Bq[4]  = *(const float4v*)(bp + 4);
        *(float4v*)&Bq[8]  = *(const float4v*)(bp + 8);
        *(float4v*)&Bq[12] = *(const float4v*)(bp + 12);
        float du = dl * uu;
        sdl += dl;
#pragma unroll
        for (int n = 0; n < NS; n++) {
            float a = exp2f(dl * Al2[n]);
            S[n] = fmaf(a, S[n], du * Bq[n]);
        }
    }
    const size_t o = (((size_t)b * NC + c) * DI + d) * NS;
#pragma unroll
    for (int n = 0; n < NS; n += 4)
        *(float4v*)(Sws + o + n) = *(const float4v*)&S[n];
    float P[NS];
#pragma unroll
    for (int n = 0; n < NS; n++) P[n] = exp2f(Al2[n] * sdl);
#pragma unroll
    for (int n = 0; n < NS; n += 4)
        *(float4v*)(Pws + o + n) = *(const float4v*)&P[n];
}

// ---------------- chunk combine (in place): S[c] <- state entering chunk c ----------------
__global__ __launch_bounds__(256) void scan_mid(const float* __restrict__ Pws,
                                                float* __restrict__ Sio) {
    const int i = blockIdx.x * 256 + threadIdx.x;  // over NBATCH*DI*NS
    const int b = i / (DI * NS);
    const int dn = i % (DI * NS);
    float h = 0.f;
#pragma unroll 4
    for (int c = 0; c < NC; ++c) {
        const size_t o = ((size_t)(b * NC + c) * DI * NS) + dn;
        float s = Sio[o];
        float p = Pws[o];
        Sio[o] = h;
        h = fmaf(p, h, s);
    }
}

// ---------------- scan pass 2 (lane-owns-d): re-scan from Hin, emit gated y ----------------
__global__ __launch_bounds__(256) void scan_p2(const float* __restrict__ delta,
                                               const short* __restrict__ ub,
                                               const float* __restrict__ dbc,
                                               const short* __restrict__ alog,
                                               const short* __restrict__ dpar,
                                               const short* __restrict__ resb,
                                               const float* __restrict__ Hin,
                                               short* __restrict__ yb) {
    const int c = blockIdx.x;
    const int b = blockIdx.y / 6;
    const int dblk = blockIdx.y % 6;
    const int d = dblk * 256 + threadIdx.x;

    float Al2[NS];
    {
        short8 a0 = *(const short8*)(alog + (size_t)d * NS);
        short8 a1 = *(const short8*)(alog + (size_t)d * NS + 8);
#pragma unroll
        for (int n = 0; n < 8; n++) {
            Al2[n]     = -__expf(bf2f(a0[n])) * 1.44269504f;
            Al2[n + 8] = -__expf(bf2f(a1[n])) * 1.44269504f;
        }
    }
    const float Dd = bf2f(dpar[d]);
    float h[NS];
    {
        const size_t o = (((size_t)b * NC + c) * DI + d) * NS;
#pragma unroll
        for (int n = 0; n < NS; n += 4)
            *(float4v*)&h[n] = *(const float4v*)(Hin + o + n);
    }
    const size_t tok0 = (size_t)b * LSEQ + (size_t)c * LC;
#pragma unroll 2
    for (int t = 0; t < LC; ++t) {
        const size_t tok = tok0 + t;
        float dl = delta[tok * DI + d];
        float uu = bf2f(ub[tok * DI + d]);
        float rr = bf2f(resb[tok * DI + d]);
        const float* bp = dbc + tok * DBCW + DTR;
        float Bq[NS], Cq[NS];
        *(float4v*)&Bq[0]  = *(const float4v*)(bp);
        *(float4v*)&Bq[4]  = *(const float4v*)(bp + 4);
        *(float4v*)&Bq[8]  = *(const float4v*)(bp + 8);
        *(float4v*)&Bq[12] = *(const float4v*)(bp + 12);
        *(float4v*)&Cq[0]  = *(const float4v*)(bp + 16);
        *(float4v*)&Cq[4]  = *(const float4v*)(bp + 20);
        *(float4v*)&Cq[8]  = *(const float4v*)(bp + 24);
        *(float4v*)&Cq[12] = *(const float4v*)(bp + 28);
        float du = dl * uu;
        float y0 = 0.f, y1 = 0.f, y2 = 0.f, y3 = 0.f;
#pragma unroll
        for (int n = 0; n < NS; n += 4) {
            float a0 = exp2f(dl * Al2[n]);
            float a1 = exp2f(dl * Al2[n + 1]);
            float a2 = exp2f(dl * Al2[n + 2]);
            float a3 = exp2f(dl * Al2[n + 3]);
            h[n]     = fmaf(a0, h[n],     du * Bq[n]);
            h[n + 1] = fmaf(a1, h[n + 1], du * Bq[n + 1]);
            h[n + 2] = fmaf(a2, h[n + 2], du * Bq[n + 2]);
            h[n + 3] = fmaf(a3, h[n + 3], du * Bq[n + 3]);
            y0 = fmaf(h[n],     Cq[n],     y0);
            y1 = fmaf(h[n + 1], Cq[n + 1], y1);
            y2 = fmaf(h[n + 2], Cq[n + 2], y2);
            y3 = fmaf(h[n + 3], Cq[n + 3], y3);
        }
        float y = (y0 + y1) + (y2 + y3) + uu * Dd;
        yb[tok * DI + d] = f2bf(y * silu(rr));
    }
}

extern "C" void kernel_launch(void* const* d_in, const int* in_sizes, int n_in,
                              void* d_out, int out_size, void* d_ws, size_t ws_size,
                              hipStream_t stream) {
    char* ws = (char*)d_ws;
    size_t off = 0;
    auto take = [&](size_t bytes) { char* p = ws + off; off = (off + bytes + 255) & ~(size_t)255; return p; };
    int*   flag = (int*)take(4);
    short* canon = (short*)take((size_t)O_TOT * 2);
    short* xn   = (short*)take((size_t)NT * DM * 2);
    short* xinb = (short*)take((size_t)NT * DI * 2);    // dead after conv; reused as Pws
    short* res  = (short*)take((size_t)NT * DI * 2);
    short* ub   = (short*)take((size_t)NT * DI * 2);
    float* dbc  = (float*)take((size_t)NT * DBCW * 4);
    float* delt = (float*)take((size_t)NT * DI * 4);
    short* yb   = (short*)take((size_t)NT * DI * 2);
    float* Sws  = (float*)take((size_t)NBATCH * NC * DI * NS * 4);  // 12.58 MB; doubles as Hin
    // alias: Pws needs 2*64*1536*16*4 = 12582912 B == NT*DI*2 (xinb), lifetimes disjoint
    float* Pws = (float*)xinb;

    const short* cx    = canon + O_X;
    const short* clnw  = canon + O_LNW;
    const short* clnb  = canon + O_LNB;
    const short* cinw  = canon + O_INW;
    const short* ccw   = canon + O_CW;
    const short* ccb   = canon + O_CB;
    const short* cxpw  = canon + O_XPW;
    const short* cdtw  = canon + O_DTW;
    const short* cdtb  = canon + O_DTB;
    const short* calog = canon + O_ALOG;
    const short* cdpar = canon + O_DPAR;
    const short* coutw = canon + O_OUTW;

    detect_kernel<<<1, 64, 0, stream>>>((const unsigned short*)d_in[0], flag);
    canon_kernel<<<(O_TOT + 255) / 256, 256, 0, stream>>>(
        d_in[0], d_in[1], d_in[2], d_in[3], d_in[4], d_in[5],
        d_in[6], d_in[7], d_in[8], d_in[9], d_in[10], d_in[11], flag, canon);

    ln_kernel<<<NT / 4, 256, 0, stream>>>(cx, clnw, clnb, xn);
    gemm128<0><<<dim3(3072 / 128, NT / 128), 256, 0, stream>>>(xn, cinw, DM, nullptr, xinb, res, nullptr);
    conv_kernel<<<NT * DI / 256, 256, 0, stream>>>(xinb, ccw, ccb, ub);
    gemm_small<<<dim3(2, NT / 64), 256, 0, stream>>>(ub, cxpw, DBCW, DI, dbc);
    dtproj_kernel<<<NT, 256, 0, stream>>>(dbc, cdtw, cdtb, delt);

    scan_p1<<<dim3(NC, NBATCH * 6), 256, 0, stream>>>(delt, ub, dbc, calog, Pws, Sws);
    scan_mid<<<NBATCH * DI * NS / 256, 256, 0, stream>>>(Pws, Sws);
    scan_p2<<<dim3(NC, NBATCH * 6), 256, 0, stream>>>(delt, ub, dbc, calog, cdpar, res, Sws, yb);

    gemm128<2><<<dim3(DM / 128, NT / 128), 256, 0, stream>>>(yb, coutw, DI,
                                                             (float*)d_out, (short*)d_out, nullptr, flag);
}

// Round 7
// 345.318 us; speedup vs baseline: 5.2214x; 1.0159x over previous
//
#include <hip/hip_runtime.h>

#define NT 4096      // B*L tokens
#define DM 768
#define DI 1536
#define LSEQ 2048
#define NBATCH 2
#define DTR 48
#define NS 16
#define NC 64        // scan chunks
#define LC 32        // chunk length (LSEQ/NC)

// canonical input segment offsets (elements)
#define O_X    0
#define O_LNW  3145728
#define O_LNB  3146496
#define O_INW  3147264
#define O_CW   5506560
#define O_CB   5512704
#define O_XPW  5514240
#define O_DTW  5637120
#define O_DTB  5710848
#define O_ALOG 5712384
#define O_DPAR 5736960
#define O_OUTW 5738496
#define O_TOT  6918144

typedef __attribute__((ext_vector_type(8))) short short8;
typedef __attribute__((ext_vector_type(4))) float float4v;

__device__ __forceinline__ float bf2f(short s) {
    union { unsigned int u; float f; } c; c.u = ((unsigned int)(unsigned short)s) << 16; return c.f;
}
__device__ __forceinline__ float bflo(unsigned int u) {
    union { unsigned int u; float f; } c; c.u = u << 16; return c.f;
}
__device__ __forceinline__ float bfhi(unsigned int u) {
    union { unsigned int u; float f; } c; c.u = u & 0xffff0000u; return c.f;
}
__device__ __forceinline__ short f2bf(float f) {
    union { unsigned int u; float f; } c; c.f = f;
    unsigned int lsb = (c.u >> 16) & 1u;
    unsigned int r = c.u + 0x7fffu + lsb;
    return (short)(r >> 16);
}
__device__ __forceinline__ float silu(float x) { return x / (1.f + __expf(-x)); }

// ---------------- dtype detection: even-index shorts of x ----------------
__global__ void detect_kernel(const unsigned short* __restrict__ x, int* __restrict__ flag) {
    int lane = threadIdx.x & 63;
    unsigned short s = x[lane * 2];
    int e = (s >> 7) & 0xFF;
    bool plaus = (e >= 100 && e <= 140);
    unsigned long long m = __ballot(plaus);
    if (lane == 0) *flag = (__popcll(m) >= 32) ? 0 : 1;  // 0=bf16, 1=f32
}

// ---------------- canonicalize all inputs into one bf16 buffer ----------------
__global__ __launch_bounds__(256) void canon_kernel(
    const void* s0, const void* s1, const void* s2, const void* s3,
    const void* s4, const void* s5, const void* s6, const void* s7,
    const void* s8, const void* s9, const void* s10, const void* s11,
    const int* __restrict__ flag, short* __restrict__ canon) {
    int i = blockIdx.x * 256 + threadIdx.x;
    if (i >= O_TOT) return;
    const void* src; int j;
    if      (i < O_LNW)  { src = s0;  j = i; }
    else if (i < O_LNB)  { src = s1;  j = i - O_LNW; }
    else if (i < O_INW)  { src = s2;  j = i - O_LNB; }
    else if (i < O_CW)   { src = s3;  j = i - O_INW; }
    else if (i < O_CB)   { src = s4;  j = i - O_CW; }
    else if (i < O_XPW)  { src = s5;  j = i - O_CB; }
    else if (i < O_DTW)  { src = s6;  j = i - O_XPW; }
    else if (i < O_DTB)  { src = s7;  j = i - O_DTW; }
    else if (i < O_ALOG) { src = s8;  j = i - O_DTB; }
    else if (i < O_DPAR) { src = s9;  j = i - O_ALOG; }
    else if (i < O_OUTW) { src = s10; j = i - O_DPAR; }
    else                 { src = s11; j = i - O_OUTW; }
    short v;
    if (*flag) v = f2bf(((const float*)src)[j]);
    else       v = ((const short*)src)[j];
    canon[i] = v;
}

// ---------------- pad dt_proj_w [1536x48] -> [1536x64] bf16 (zeros in 48..63) --------
__global__ __launch_bounds__(256) void pad_dtw_kernel(const short* __restrict__ w,
                                                      short* __restrict__ wp) {
    int i = blockIdx.x * 256 + threadIdx.x;  // over 1536*64, exact
    int d = i >> 6, j = i & 63;
    wp[i] = (j < DTR) ? w[d * DTR + j] : (short)0;
}

// ---------------- LayerNorm: one wave per token ----------------
__global__ __launch_bounds__(256) void ln_kernel(const short* __restrict__ x,
                                                 const short* __restrict__ w,
                                                 const short* __restrict__ b,
                                                 short* __restrict__ xn) {
    const int wave = threadIdx.x >> 6, lane = threadIdx.x & 63;
    const int token = blockIdx.x * 4 + wave;
    const short* xr = x + (size_t)token * DM;
    short* xo = xn + (size_t)token * DM;
    float vals[12];
    float s = 0.f, s2 = 0.f;
#pragma unroll
    for (int j = 0; j < 6; j++) {
        unsigned int u = *(const unsigned int*)(xr + lane * 2 + j * 128);
        float f0 = bflo(u), f1 = bfhi(u);
        vals[2 * j] = f0; vals[2 * j + 1] = f1;
        s += f0 + f1; s2 += f0 * f0 + f1 * f1;
    }
#pragma unroll
    for (int off = 1; off < 64; off <<= 1) {
        s += __shfl_xor(s, off);
        s2 += __shfl_xor(s2, off);
    }
    const float mu = s * (1.f / DM);
    const float var = s2 * (1.f / DM) - mu * mu;
    const float rs = rsqrtf(var + 1e-5f);
#pragma unroll
    for (int j = 0; j < 6; j++) {
        int e = lane * 2 + j * 128;
        unsigned int uw = *(const unsigned int*)(w + e);
        unsigned int ub = *(const unsigned int*)(b + e);
        float o0 = (vals[2 * j] - mu) * rs * bflo(uw) + bflo(ub);
        float o1 = (vals[2 * j + 1] - mu) * rs * bfhi(uw) + bfhi(ub);
        unsigned int pk = (unsigned int)(unsigned short)f2bf(o0) |
                          ((unsigned int)(unsigned short)f2bf(o1) << 16);
        *(unsigned int*)(xo + e) = pk;
    }
}

// ---------------- 128x128 bf16 MFMA GEMM: C[m,n] = sum_k A[m,k]*B[n,k] ----------------
// MODE 0: in_proj split: n<DI -> outS bf16 (stride DI), else outS2 (stride DI)
// MODE 2: out_proj: *oflag ? f32 outF : bf16 outS, stride DM
// MODE 3: dt_proj: outF[m*DI+n] = softplus(v + bias[n]); bias passed via outS
template <int MODE>
__global__ __launch_bounds__(256) void gemm128(const short* __restrict__ A,
                                               const short* __restrict__ B,
                                               int K,
                                               float* __restrict__ outF,
                                               short* __restrict__ outS,
                                               short* __restrict__ outS2,
                                               const int* __restrict__ oflag) {
    __shared__ short As[128 * 40];
    __shared__ short Bs[128 * 40];
    const int tid = threadIdx.x;
    const int wave = tid >> 6, lane = tid & 63;
    const int mBase = blockIdx.y * 128, nBase = blockIdx.x * 128;
    const int l15 = lane & 15, quad = lane >> 4;
    const int wm = (wave >> 1) * 64;
    const int wn = (wave & 1) * 64;
    const int srow = tid >> 2;          // 0..63
    const int scol = (tid & 3) * 8;     // 0,8,16,24
    const short* aP = A + (size_t)(mBase + srow) * K + scol;
    const short* bP = B + (size_t)(nBase + srow) * K + scol;
    const size_t half = (size_t)64 * K;

    float4v acc[4][4] = {};

    for (int k0 = 0; k0 < K; k0 += 32) {
        short8 a0 = *(const short8*)(aP + k0);
        short8 a1 = *(const short8*)(aP + half + k0);
        short8 b0 = *(const short8*)(bP + k0);
        short8 b1 = *(const short8*)(bP + half + k0);
        __syncthreads();
        *(short8*)&As[srow * 40 + scol] = a0;
        *(short8*)&As[(srow + 64) * 40 + scol] = a1;
        *(short8*)&Bs[srow * 40 + scol] = b0;
        *(short8*)&Bs[(srow + 64) * 40 + scol] = b1;
        __syncthreads();
        short8 af[4], bf[4];
#pragma unroll
        for (int i = 0; i < 4; i++) {
            af[i] = *(const short8*)&As[(wm + i * 16 + l15) * 40 + quad * 8];
            bf[i] = *(const short8*)&Bs[(wn + i * 16 + l15) * 40 + quad * 8];
        }
#pragma unroll
        for (int i = 0; i < 4; i++)
#pragma unroll
            for (int j = 0; j < 4; j++)
                acc[i][j] = __builtin_amdgcn_mfma_f32_16x16x32_bf16(af[i], bf[j], acc[i][j], 0, 0, 0);
    }

    const bool outf32 = (MODE == 2) ? (*oflag != 0) : false;
#pragma unroll
    for (int i = 0; i < 4; i++)
#pragma unroll
        for (int j = 0; j < 4; j++)
#pragma unroll
            for (int r = 0; r < 4; r++) {
                int m = mBase + wm + i * 16 + quad * 4 + r;
                int n = nBase + wn + j * 16 + l15;
                float v = acc[i][j][r];
                if (MODE == 0) {
                    if (n < DI) outS[(size_t)m * DI + n] = f2bf(v);
                    else outS2[(size_t)m * DI + (n - DI)] = f2bf(v);
                } else if (MODE == 2) {
                    if (outf32) outF[(size_t)m * DM + n] = v;
                    else outS[(size_t)m * DM + n] = f2bf(v);
                } else {
                    float s = v + bf2f(((const short*)outS)[n]);
                    float sp = (s > 20.f) ? s : log1pf(__expf(s));
                    outF[(size_t)m * DI + n] = sp;
                }
            }
}

// ---------------- 64-tile GEMM for x_proj (N=80): dt->bf16 dtb[4096x64], B/C->f32 bcf[4096x32] ---
__global__ __launch_bounds__(256) void gemm_small(const short* __restrict__ A,
                                                  const short* __restrict__ B,
                                                  int N, int K,
                                                  short* __restrict__ dtb,
                                                  float* __restrict__ bcf) {
    __shared__ short As[64 * 40];
    __shared__ short Bs[64 * 40];
    const int tid = threadIdx.x;
    const int mBase = blockIdx.y * 64;
    const int nBase = blockIdx.x * 64;
    const int lrow = tid >> 2;
    const int lcol = (tid & 3) * 8;
    const int wave = tid >> 6;
    const int lane = tid & 63;
    const int l15 = lane & 15;
    const int quad = lane >> 4;
    const int wm = (wave >> 1) * 32;
    const int wn = (wave & 1) * 32;

    float4v acc[2][2] = {};

    const bool bvalid = (nBase + lrow) < N;
    const short* aptr = A + (size_t)(mBase + lrow) * K + lcol;
    const short* bptr = B + (size_t)(nBase + lrow) * K + lcol;
    const short8 bz = {0, 0, 0, 0, 0, 0, 0, 0};

    for (int k0 = 0; k0 < K; k0 += 32) {
        short8 av = *(const short8*)(aptr + k0);
        short8 bv = bvalid ? *(const short8*)(bptr + k0) : bz;
        __syncthreads();
        *(short8*)&As[lrow * 40 + lcol] = av;
        *(short8*)&Bs[lrow * 40 + lcol] = bv;
        __syncthreads();
        short8 a0 = *(const short8*)&As[(wm + l15) * 40 + quad * 8];
        short8 a1 = *(const short8*)&As[(wm + 16 + l15) * 40 + quad * 8];
        short8 b0 = *(const short8*)&Bs[(wn + l15) * 40 + quad * 8];
        short8 b1 = *(const short8*)&Bs[(wn + 16 + l15) * 40 + quad * 8];
        acc[0][0] = __builtin_amdgcn_mfma_f32_16x16x32_bf16(a0, b0, acc[0][0], 0, 0, 0);
        acc[0][1] = __builtin_amdgcn_mfma_f32_16x16x32_bf16(a0, b1, acc[0][1], 0, 0, 0);
        acc[1][0] = __builtin_amdgcn_mfma_f32_16x16x32_bf16(a1, b0, acc[1][0], 0, 0, 0);
        acc[1][1] = __builtin_amdgcn_mfma_f32_16x16x32_bf16(a1, b1, acc[1][1], 0, 0, 0);
    }

#pragma unroll
    for (int i = 0; i < 2; i++)
#pragma unroll
        for (int j = 0; j < 2; j++)
#pragma unroll
            for (int r = 0; r < 4; r++) {
                int m = mBase + wm + i * 16 + quad * 4 + r;
                int n = nBase + wn + j * 16 + l15;
                float v = acc[i][j][r];
                if (n < DTR) {
                    dtb[(size_t)m * 64 + n] = f2bf(v);
                } else if (n < 64) {
                    dtb[(size_t)m * 64 + n] = (short)0;
                    bcf[(size_t)m * 32 + (n - DTR)] = v;
                } else if (n < 80) {
                    bcf[(size_t)m * 32 + (n - DTR)] = v;
                }
            }
}

// ---------------- depthwise causal conv (taps=4) + SiLU ----------------
__global__ __launch_bounds__(256) void conv_kernel(const short* __restrict__ xin,
                                                   const short* __restrict__ cw,
                                                   const short* __restrict__ cb,
                                                   short* __restrict__ ub) {
    const int idx = blockIdx.x * 256 + threadIdx.x;  // over NT*DI, exact
    const int d = idx % DI;
    const int t = idx / DI;
    const int l = t % LSEQ;
    float s = bf2f(cb[d]);
#pragma unroll
    for (int j = 0; j < 4; j++) {
        int lj = l - 3 + j;
        if (lj >= 0) s += bf2f(xin[(size_t)(t - 3 + j) * DI + d]) * bf2f(cw[d * 4 + j]);
    }
    float u = silu(s);
    ub[idx] = f2bf(u);
}

// ---------------- scan pass 1 (lane-owns-d): chunk summary S, P via log-space ----------------
__global__ __launch_bounds__(256) void scan_p1(const float* __restrict__ delta,
                                               const short* __restrict__ ub,
                                               const float* __restrict__ bcf,
                                               const short* __restrict__ alog,
                                               float* __restrict__ Pws,
                                               float* __restrict__ Sws) {
    const int c = blockIdx.x;
    const int b = blockIdx.y / 6;
    const int dblk = blockIdx.y % 6;
    const int d = dblk * 256 + threadIdx.x;

    float Al2[NS];
    {
        short8 a0 = *(const short8*)(alog + (size_t)d * NS);
        short8 a1 = *(const short8*)(alog + (size_t)d * NS + 8);
#pragma unroll
        for (int n = 0; n < 8; n++) {
            Al2[n]     = -__expf(bf2f(a0[n])) * 1.44269504f;
            Al2[n + 8] = -__expf(bf2f(a1[n])) * 1.44269504f;
        }
    }
    float S[NS];
#pragma unroll
    for (int n = 0; n < NS; n++) S[n] = 0.f;
    float sdl = 0.f;
    const size_t tok0 = (size_t)b * LSEQ + (size_t)c * LC;
#pragma unroll 2
    for (int t = 0; t < LC; ++t) {
        const size_t tok = tok0 + t;
        float dl = delta[tok * DI + d];
        float uu = bf2f(ub[tok * DI + d]);
        const float* bp = bcf + tok * 32;
        float Bq[NS];
        *(float4v*)&Bq[0]  = *(const float4v*)(bp);
        *(float4v*)&Bq[4]  = *(const float4v*)(bp + 4);
        *(float4v*)&Bq[8]  = *(const float4v*)(bp + 8);
        *(float4v*)&Bq[12] = *(const float4v*)(bp + 12);
        float du = dl * uu;
        sdl += dl;
#pragma unroll
        for (int n = 0; n < NS; n++) {
            float a = exp2f(dl * Al2[n]);
            S[n] = fmaf(a, S[n], du * Bq[n]);
        }
    }
    const size_t o = (((size_t)b * NC + c) * DI + d) * NS;
#pragma unroll
    for (int n = 0; n < NS; n += 4)
        *(float4v*)(Sws + o + n) = *(const float4v*)&S[n];
    float P[NS];
#pragma unroll
    for (int n = 0; n < NS; n++) P[n] = exp2f(Al2[n] * sdl);
#pragma unroll
    for (int n = 0; n < NS; n += 4)
        *(float4v*)(Pws + o + n) = *(const float4v*)&P[n];
}

// ---------------- chunk combine (in place): S[c] <- state entering chunk c ----------------
__global__ __launch_bounds__(256) void scan_mid(const float* __restrict__ Pws,
                                                float* __restrict__ Sio) {
    const int i = blockIdx.x * 256 + threadIdx.x;  // over NBATCH*DI*NS
    const int b = i / (DI * NS);
    const int dn = i % (DI * NS);
    float h = 0.f;
#pragma unroll 4
    for (int c = 0; c < NC; ++c) {
        const size_t o = ((size_t)(b * NC + c) * DI * NS) + dn;
        float s = Sio[o];
        float p = Pws[o];
        Sio[o] = h;
        h = fmaf(p, h, s);
    }
}

// ---------------- scan pass 2 (lane-owns-d): re-scan from Hin, emit gated y ----------------
__global__ __launch_bounds__(256) void scan_p2(const float* __restrict__ delta,
                                               const short* __restrict__ ub,
                                               const float* __restrict__ bcf,
                                               const short* __restrict__ alog,
                                               const short* __restrict__ dpar,
                                               const short* __restrict__ resb,
                                               const float* __restrict__ Hin,
                                               short* __restrict__ yb) {
    const int c = blockIdx.x;
    const int b = blockIdx.y / 6;
    const int dblk = blockIdx.y % 6;
    const int d = dblk * 256 + threadIdx.x;

    float Al2[NS];
    {
        short8 a0 = *(const short8*)(alog + (size_t)d * NS);
        short8 a1 = *(const short8*)(alog + (size_t)d * NS + 8);
#pragma unroll
        for (int n = 0; n < 8; n++) {
            Al2[n]     = -__expf(bf2f(a0[n])) * 1.44269504f;
            Al2[n + 8] = -__expf(bf2f(a1[n])) * 1.44269504f;
        }
    }
    const float Dd = bf2f(dpar[d]);
    float h[NS];
    {
        const size_t o = (((size_t)b * NC + c) * DI + d) * NS;
#pragma unroll
        for (int n = 0; n < NS; n += 4)
            *(float4v*)&h[n] = *(const float4v*)(Hin + o + n);
    }
    const size_t tok0 = (size_t)b * LSEQ + (size_t)c * LC;
#pragma unroll 2
    for (int t = 0; t < LC; ++t) {
        const size_t tok = tok0 + t;
        float dl = delta[tok * DI + d];
        float uu = bf2f(ub[tok * DI + d]);
        float rr = bf2f(resb[tok * DI + d]);
        const float* bp = bcf + tok * 32;
        float Bq[NS], Cq[NS];
        *(float4v*)&Bq[0]  = *(const float4v*)(bp);
        *(float4v*)&Bq[4]  = *(const float4v*)(bp + 4);
        *(float4v*)&Bq[8]  = *(const float4v*)(bp + 8);
        *(float4v*)&Bq[12] = *(const float4v*)(bp + 12);
        *(float4v*)&Cq[0]  = *(const float4v*)(bp + 16);
        *(float4v*)&Cq[4]  = *(const float4v*)(bp + 20);
        *(float4v*)&Cq[8]  = *(const float4v*)(bp + 24);
        *(float4v*)&Cq[12] = *(const float4v*)(bp + 28);
        float du = dl * uu;
        float y0 = 0.f, y1 = 0.f, y2 = 0.f, y3 = 0.f;
#pragma unroll
        for (int n = 0; n < NS; n += 4) {
            float a0 = exp2f(dl * Al2[n]);
            float a1 = exp2f(dl * Al2[n + 1]);
            float a2 = exp2f(dl * Al2[n + 2]);
            float a3 = exp2f(dl * Al2[n + 3]);
            h[n]     = fmaf(a0, h[n],     du * Bq[n]);
            h[n + 1] = fmaf(a1, h[n + 1], du * Bq[n + 1]);
            h[n + 2] = fmaf(a2, h[n + 2], du * Bq[n + 2]);
            h[n + 3] = fmaf(a3, h[n + 3], du * Bq[n + 3]);
            y0 = fmaf(h[n],     Cq[n],     y0);
            y1 = fmaf(h[n + 1], Cq[n + 1], y1);
            y2 = fmaf(h[n + 2], Cq[n + 2], y2);
            y3 = fmaf(h[n + 3], Cq[n + 3], y3);
        }
        float y = (y0 + y1) + (y2 + y3) + uu * Dd;
        yb[tok * DI + d] = f2bf(y * silu(rr));
    }
}

extern "C" void kernel_launch(void* const* d_in, const int* in_sizes, int n_in,
                              void* d_out, int out_size, void* d_ws, size_t ws_size,
                              hipStream_t stream) {
    char* ws = (char*)d_ws;
    size_t off = 0;
    auto take = [&](size_t bytes) { char* p = ws + off; off = (off + bytes + 255) & ~(size_t)255; return p; };
    int*   flag = (int*)take(4);
    short* canon = (short*)take((size_t)O_TOT * 2);
    short* xn   = (short*)take((size_t)NT * DM * 2);
    short* xinb = (short*)take((size_t)NT * DI * 2);    // dead after conv; reused as Pws
    short* res  = (short*)take((size_t)NT * DI * 2);
    short* ub   = (short*)take((size_t)NT * DI * 2);
    short* dtb  = (short*)take((size_t)NT * 64 * 2);
    float* bcf  = (float*)take((size_t)NT * 32 * 4);
    short* dtwp = (short*)take((size_t)DI * 64 * 2);
    float* delt = (float*)take((size_t)NT * DI * 4);
    short* yb   = (short*)take((size_t)NT * DI * 2);
    float* Sws  = (float*)take((size_t)NBATCH * NC * DI * NS * 4);  // 12.58 MB; doubles as Hin
    // alias: Pws needs 2*64*1536*16*4 = 12582912 B == NT*DI*2 (xinb), lifetimes disjoint
    float* Pws = (float*)xinb;

    const short* cx    = canon + O_X;
    const short* clnw  = canon + O_LNW;
    const short* clnb  = canon + O_LNB;
    const short* cinw  = canon + O_INW;
    const short* ccw   = canon + O_CW;
    const short* ccb   = canon + O_CB;
    const short* cxpw  = canon + O_XPW;
    const short* cdtw  = canon + O_DTW;
    const short* cdtb  = canon + O_DTB;
    const short* calog = canon + O_ALOG;
    const short* cdpar = canon + O_DPAR;
    const short* coutw = canon + O_OUTW;

    detect_kernel<<<1, 64, 0, stream>>>((const unsigned short*)d_in[0], flag);
    canon_kernel<<<(O_TOT + 255) / 256, 256, 0, stream>>>(
        d_in[0], d_in[1], d_in[2], d_in[3], d_in[4], d_in[5],
        d_in[6], d_in[7], d_in[8], d_in[9], d_in[10], d_in[11], flag, canon);

    ln_kernel<<<NT / 4, 256, 0, stream>>>(cx, clnw, clnb, xn);
    gemm128<0><<<dim3(3072 / 128, NT / 128), 256, 0, stream>>>(xn, cinw, DM, nullptr, xinb, res, nullptr);
    conv_kernel<<<NT * DI / 256, 256, 0, stream>>>(xinb, ccw, ccb, ub);
    pad_dtw_kernel<<<DI * 64 / 256, 256, 0, stream>>>(cdtw, dtwp);
    gemm_small<<<dim3(2, NT / 64), 256, 0, stream>>>(ub, cxpw, 80, DI, dtb, bcf);
    gemm128<3><<<dim3(DI / 128, NT / 128), 256, 0, stream>>>(dtb, dtwp, 64, delt, (short*)cdtb, nullptr, nullptr);

    scan_p1<<<dim3(NC, NBATCH * 6), 256, 0, stream>>>(delt, ub, bcf, calog, Pws, Sws);
    scan_mid<<<NBATCH * DI * NS / 256, 256, 0, stream>>>(Pws, Sws);
    scan_p2<<<dim3(NC, NBATCH * 6), 256, 0, stream>>>(delt, ub, bcf, calog, cdpar, res, Sws, yb);

    gemm128<2><<<dim3(DM / 128, NT / 128), 256, 0, stream>>>(yb, coutw, DI,
                                                             (float*)d_out, (short*)d_out, nullptr, flag);
}

// Round 8
// 329.575 us; speedup vs baseline: 5.4708x; 1.0478x over previous
//
#include <hip/hip_runtime.h>

#define NT 4096      // B*L tokens
#define DM 768
#define DI 1536
#define LSEQ 2048
#define NBATCH 2
#define DTR 48
#define NS 16
#define NC 64        // scan chunks
#define LC 32        // chunk length (LSEQ/NC)

// canonical input segment offsets (elements)
#define O_X    0
#define O_LNW  3145728
#define O_LNB  3146496
#define O_INW  3147264
#define O_CW   5506560
#define O_CB   5512704
#define O_XPW  5514240
#define O_DTW  5637120
#define O_DTB  5710848
#define O_ALOG 5712384
#define O_DPAR 5736960
#define O_OUTW 5738496
#define O_TOT  6918144
#define PAD_EXTRA (DI * 16)   // zero-fill region for dtwp cols 48..63

typedef __attribute__((ext_vector_type(8))) short short8;
typedef __attribute__((ext_vector_type(4))) float float4v;

__device__ __forceinline__ float bf2f(short s) {
    union { unsigned int u; float f; } c; c.u = ((unsigned int)(unsigned short)s) << 16; return c.f;
}
__device__ __forceinline__ float bflo(unsigned int u) {
    union { unsigned int u; float f; } c; c.u = u << 16; return c.f;
}
__device__ __forceinline__ float bfhi(unsigned int u) {
    union { unsigned int u; float f; } c; c.u = u & 0xffff0000u; return c.f;
}
__device__ __forceinline__ short f2bf(float f) {
    union { unsigned int u; float f; } c; c.f = f;
    unsigned int lsb = (c.u >> 16) & 1u;
    unsigned int r = c.u + 0x7fffu + lsb;
    return (short)(r >> 16);
}
__device__ __forceinline__ float silu(float x) { return x / (1.f + __expf(-x)); }

// ---------------- dtype detection: even-index shorts of x ----------------
__global__ void detect_kernel(const unsigned short* __restrict__ x, int* __restrict__ flag) {
    int lane = threadIdx.x & 63;
    unsigned short s = x[lane * 2];
    int e = (s >> 7) & 0xFF;
    bool plaus = (e >= 100 && e <= 140);
    unsigned long long m = __ballot(plaus);
    if (lane == 0) *flag = (__popcll(m) >= 32) ? 0 : 1;  // 0=bf16, 1=f32
}

// ------- canonicalize all inputs into bf16 buffer; also build padded dt_proj_w [1536x64] -------
__global__ __launch_bounds__(256) void canon_kernel(
    const void* s0, const void* s1, const void* s2, const void* s3,
    const void* s4, const void* s5, const void* s6, const void* s7,
    const void* s8, const void* s9, const void* s10, const void* s11,
    const int* __restrict__ flag, short* __restrict__ canon,
    short* __restrict__ dtwp) {
    int i = blockIdx.x * 256 + threadIdx.x;
    if (i >= O_TOT) {
        int i2 = i - O_TOT;
        if (i2 < PAD_EXTRA) dtwp[(i2 >> 4) * 64 + 48 + (i2 & 15)] = 0;
        return;
    }
    const void* src; int j;
    if      (i < O_LNW)  { src = s0;  j = i; }
    else if (i < O_LNB)  { src = s1;  j = i - O_LNW; }
    else if (i < O_INW)  { src = s2;  j = i - O_LNB; }
    else if (i < O_CW)   { src = s3;  j = i - O_INW; }
    else if (i < O_CB)   { src = s4;  j = i - O_CW; }
    else if (i < O_XPW)  { src = s5;  j = i - O_CB; }
    else if (i < O_DTW)  { src = s6;  j = i - O_XPW; }
    else if (i < O_DTB)  { src = s7;  j = i - O_DTW; }
    else if (i < O_ALOG) { src = s8;  j = i - O_DTB; }
    else if (i < O_DPAR) { src = s9;  j = i - O_ALOG; }
    else if (i < O_OUTW) { src = s10; j = i - O_DPAR; }
    else                 { src = s11; j = i - O_OUTW; }
    short v;
    if (*flag) v = f2bf(((const float*)src)[j]);
    else       v = ((const short*)src)[j];
    canon[i] = v;
    if (i >= O_DTW && i < O_DTB) {
        int jj = i - O_DTW;
        dtwp[(jj / DTR) * 64 + (jj % DTR)] = v;
    }
}

// ---------------- LayerNorm: one wave per token ----------------
__global__ __launch_bounds__(256) void ln_kernel(const short* __restrict__ x,
                                                 const short* __restrict__ w,
                                                 const short* __restrict__ b,
                                                 short* __restrict__ xn) {
    const int wave = threadIdx.x >> 6, lane = threadIdx.x & 63;
    const int token = blockIdx.x * 4 + wave;
    const short* xr = x + (size_t)token * DM;
    short* xo = xn + (size_t)token * DM;
    float vals[12];
    float s = 0.f, s2 = 0.f;
#pragma unroll
    for (int j = 0; j < 6; j++) {
        unsigned int u = *(const unsigned int*)(xr + lane * 2 + j * 128);
        float f0 = bflo(u), f1 = bfhi(u);
        vals[2 * j] = f0; vals[2 * j + 1] = f1;
        s += f0 + f1; s2 += f0 * f0 + f1 * f1;
    }
#pragma unroll
    for (int off = 1; off < 64; off <<= 1) {
        s += __shfl_xor(s, off);
        s2 += __shfl_xor(s2, off);
    }
    const float mu = s * (1.f / DM);
    const float var = s2 * (1.f / DM) - mu * mu;
    const float rs = rsqrtf(var + 1e-5f);
#pragma unroll
    for (int j = 0; j < 6; j++) {
        int e = lane * 2 + j * 128;
        unsigned int uw = *(const unsigned int*)(w + e);
        unsigned int ub = *(const unsigned int*)(b + e);
        float o0 = (vals[2 * j] - mu) * rs * bflo(uw) + bflo(ub);
        float o1 = (vals[2 * j + 1] - mu) * rs * bfhi(uw) + bfhi(ub);
        unsigned int pk = (unsigned int)(unsigned short)f2bf(o0) |
                          ((unsigned int)(unsigned short)f2bf(o1) << 16);
        *(unsigned int*)(xo + e) = pk;
    }
}

// ---------------- 128x128 bf16 MFMA GEMM with register prefetch ----------------
// C[m,n] = sum_k A[m,k]*B[n,k], row strides lda/ldb.
// MODE 0: in_proj split: n<DI -> outS bf16 (stride DI), else outS2 (stride DI)
// MODE 3: dt_proj: outF[m*DI+n] = softplus(v + bias[n]); bias via outS
// MODE 4: split-K partial (gridDim.z): koff = z*K, f32 partial at outF + z*NT*DM, stride DM
template <int MODE>
__global__ __launch_bounds__(256) void gemm128(const short* __restrict__ A,
                                               const short* __restrict__ B,
                                               int K, int lda, int ldb,
                                               float* __restrict__ outF,
                                               short* __restrict__ outS,
                                               short* __restrict__ outS2) {
    __shared__ short As[128 * 40];
    __shared__ short Bs[128 * 40];
    const int tid = threadIdx.x;
    const int wave = tid >> 6, lane = tid & 63;
    const int mBase = blockIdx.y * 128, nBase = blockIdx.x * 128;
    const int l15 = lane & 15, quad = lane >> 4;
    const int wm = (wave >> 1) * 64;
    const int wn = (wave & 1) * 64;
    const int srow = tid >> 2;          // 0..63
    const int scol = (tid & 3) * 8;     // 0,8,16,24

    int koff = 0;
    float* pF = outF;
    if (MODE == 4) { koff = blockIdx.z * K; pF = outF + (size_t)blockIdx.z * NT * DM; }

    const short* aP = A + (size_t)(mBase + srow) * lda + koff + scol;
    const short* bP = B + (size_t)(nBase + srow) * ldb + koff + scol;
    const size_t halfA = (size_t)64 * lda;
    const size_t halfB = (size_t)64 * ldb;

    // prefetch tile k=0
    short8 ra0 = *(const short8*)(aP);
    short8 ra1 = *(const short8*)(aP + halfA);
    short8 rb0 = *(const short8*)(bP);
    short8 rb1 = *(const short8*)(bP + halfB);

    float4v acc[4][4] = {};

    for (int k0 = 0; k0 < K; k0 += 32) {
        __syncthreads();
        *(short8*)&As[srow * 40 + scol] = ra0;
        *(short8*)&As[(srow + 64) * 40 + scol] = ra1;
        *(short8*)&Bs[srow * 40 + scol] = rb0;
        *(short8*)&Bs[(srow + 64) * 40 + scol] = rb1;
        __syncthreads();
        const int k1 = k0 + 32;
        if (k1 < K) {                     // prefetch next tile; latency overlaps MFMA below
            ra0 = *(const short8*)(aP + k1);
            ra1 = *(const short8*)(aP + halfA + k1);
            rb0 = *(const short8*)(bP + k1);
            rb1 = *(const short8*)(bP + halfB + k1);
        }
        short8 af[4], bf[4];
#pragma unroll
        for (int i = 0; i < 4; i++) {
            af[i] = *(const short8*)&As[(wm + i * 16 + l15) * 40 + quad * 8];
            bf[i] = *(const short8*)&Bs[(wn + i * 16 + l15) * 40 + quad * 8];
        }
#pragma unroll
        for (int i = 0; i < 4; i++)
#pragma unroll
            for (int j = 0; j < 4; j++)
                acc[i][j] = __builtin_amdgcn_mfma_f32_16x16x32_bf16(af[i], bf[j], acc[i][j], 0, 0, 0);
    }

#pragma unroll
    for (int i = 0; i < 4; i++)
#pragma unroll
        for (int j = 0; j < 4; j++)
#pragma unroll
            for (int r = 0; r < 4; r++) {
                int m = mBase + wm + i * 16 + quad * 4 + r;
                int n = nBase + wn + j * 16 + l15;
                float v = acc[i][j][r];
                if (MODE == 0) {
                    if (n < DI) outS[(size_t)m * DI + n] = f2bf(v);
                    else outS2[(size_t)m * DI + (n - DI)] = f2bf(v);
                } else if (MODE == 3) {
                    float s = v + bf2f(((const short*)outS)[n]);
                    float sp = (s > 20.f) ? s : log1pf(__expf(s));
                    outF[(size_t)m * DI + n] = sp;
                } else {
                    pF[(size_t)m * DM + n] = v;
                }
            }
}

// ---------------- split-K reduce: out = p0 + p1, dtype per flag ----------------
__global__ __launch_bounds__(256) void reduce_out(const float* __restrict__ p,
                                                  const int* __restrict__ flag,
                                                  float* __restrict__ of,
                                                  short* __restrict__ os) {
    int i = blockIdx.x * 256 + threadIdx.x;  // over NT*DM, exact
    float v = p[i] + p[i + (size_t)NT * DM];
    if (*flag) of[i] = v;
    else       os[i] = f2bf(v);
}

// ---------------- 64-tile GEMM for x_proj (N=80), register prefetch ----------------
// dt -> bf16 dtb[4096x64] (cols 48..63 zero), B/C -> f32 bcf[4096x32]
__global__ __launch_bounds__(256) void gemm_small(const short* __restrict__ A,
                                                  const short* __restrict__ B,
                                                  int N, int K,
                                                  short* __restrict__ dtb,
                                                  float* __restrict__ bcf) {
    __shared__ short As[64 * 40];
    __shared__ short Bs[64 * 40];
    const int tid = threadIdx.x;
    const int mBase = blockIdx.y * 64;
    const int nBase = blockIdx.x * 64;
    const int lrow = tid >> 2;
    const int lcol = (tid & 3) * 8;
    const int wave = tid >> 6;
    const int lane = tid & 63;
    const int l15 = lane & 15;
    const int quad = lane >> 4;
    const int wm = (wave >> 1) * 32;
    const int wn = (wave & 1) * 32;

    float4v acc[2][2] = {};

    const bool bvalid = (nBase + lrow) < N;
    const short* aptr = A + (size_t)(mBase + lrow) * K + lcol;
    const short* bptr = B + (size_t)(nBase + lrow) * K + lcol;
    const short8 bz = {0, 0, 0, 0, 0, 0, 0, 0};

    short8 av = *(const short8*)(aptr);
    short8 bv = bvalid ? *(const short8*)(bptr) : bz;

    for (int k0 = 0; k0 < K; k0 += 32) {
        __syncthreads();
        *(short8*)&As[lrow * 40 + lcol] = av;
        *(short8*)&Bs[lrow * 40 + lcol] = bv;
        __syncthreads();
        const int k1 = k0 + 32;
        if (k1 < K) {
            av = *(const short8*)(aptr + k1);
            bv = bvalid ? *(const short8*)(bptr + k1) : bz;
        }
        short8 a0 = *(const short8*)&As[(wm + l15) * 40 + quad * 8];
        short8 a1 = *(const short8*)&As[(wm + 16 + l15) * 40 + quad * 8];
        short8 b0 = *(const short8*)&Bs[(wn + l15) * 40 + quad * 8];
        short8 b1 = *(const short8*)&Bs[(wn + 16 + l15) * 40 + quad * 8];
        acc[0][0] = __builtin_amdgcn_mfma_f32_16x16x32_bf16(a0, b0, acc[0][0], 0, 0, 0);
        acc[0][1] = __builtin_amdgcn_mfma_f32_16x16x32_bf16(a0, b1, acc[0][1], 0, 0, 0);
        acc[1][0] = __builtin_amdgcn_mfma_f32_16x16x32_bf16(a1, b0, acc[1][0], 0, 0, 0);
        acc[1][1] = __builtin_amdgcn_mfma_f32_16x16x32_bf16(a1, b1, acc[1][1], 0, 0, 0);
    }

#pragma unroll
    for (int i = 0; i < 2; i++)
#pragma unroll
        for (int j = 0; j < 2; j++)
#pragma unroll
            for (int r = 0; r < 4; r++) {
                int m = mBase + wm + i * 16 + quad * 4 + r;
                int n = nBase + wn + j * 16 + l15;
                float v = acc[i][j][r];
                if (n < DTR) {
                    dtb[(size_t)m * 64 + n] = f2bf(v);
                } else if (n < 64) {
                    dtb[(size_t)m * 64 + n] = (short)0;
                    bcf[(size_t)m * 32 + (n - DTR)] = v;
                } else if (n < 80) {
                    bcf[(size_t)m * 32 + (n - DTR)] = v;
                }
            }
}

// ---------------- depthwise causal conv (taps=4) + SiLU ----------------
__global__ __launch_bounds__(256) void conv_kernel(const short* __restrict__ xin,
                                                   const short* __restrict__ cw,
                                                   const short* __restrict__ cb,
                                                   short* __restrict__ ub) {
    const int idx = blockIdx.x * 256 + threadIdx.x;  // over NT*DI, exact
    const int d = idx % DI;
    const int t = idx / DI;
    const int l = t % LSEQ;
    float s = bf2f(cb[d]);
#pragma unroll
    for (int j = 0; j < 4; j++) {
        int lj = l - 3 + j;
        if (lj >= 0) s += bf2f(xin[(size_t)(t - 3 + j) * DI + d]) * bf2f(cw[d * 4 + j]);
    }
    float u = silu(s);
    ub[idx] = f2bf(u);
}

// ---------------- scan pass 1 (lane-owns-d): chunk summary S, P via log-space ----------------
__global__ __launch_bounds__(256) void scan_p1(const float* __restrict__ delta,
                                               const short* __restrict__ ub,
                                               const float* __restrict__ bcf,
                                               const short* __restrict__ alog,
                                               float* __restrict__ Pws,
                                               float* __restrict__ Sws) {
    const int c = blockIdx.x;
    const int b = blockIdx.y / 6;
    const int dblk = blockIdx.y % 6;
    const int d = dblk * 256 + threadIdx.x;

    float Al2[NS];
    {
        short8 a0 = *(const short8*)(alog + (size_t)d * NS);
        short8 a1 = *(const short8*)(alog + (size_t)d * NS + 8);
#pragma unroll
        for (int n = 0; n < 8; n++) {
            Al2[n]     = -__expf(bf2f(a0[n])) * 1.44269504f;
            Al2[n + 8] = -__expf(bf2f(a1[n])) * 1.44269504f;
        }
    }
    float S[NS];
#pragma unroll
    for (int n = 0; n < NS; n++) S[n] = 0.f;
    float sdl = 0.f;
    const size_t tok0 = (size_t)b * LSEQ + (size_t)c * LC;
#pragma unroll 2
    for (int t = 0; t < LC; ++t) {
        const size_t tok = tok0 + t;
        float dl = delta[tok * DI + d];
        float uu = bf2f(ub[tok * DI + d]);
        const float* bp = bcf + tok * 32;
        float Bq[NS];
        *(float4v*)&Bq[0]  = *(const float4v*)(bp);
        *(float4v*)&Bq[4]  = *(const float4v*)(bp + 4);
        *(float4v*)&Bq[8]  = *(const float4v*)(bp + 8);
        *(float4v*)&Bq[12] = *(const float4v*)(bp + 12);
        float du = dl * uu;
        sdl += dl;
#pragma unroll
        for (int n = 0; n < NS; n++) {
            float a = exp2f(dl * Al2[n]);
            S[n] = fmaf(a, S[n], du * Bq[n]);
        }
    }
    const size_t o = (((size_t)b * NC + c) * DI + d) * NS;
#pragma unroll
    for (int n = 0; n < NS; n += 4)
        *(float4v*)(Sws + o + n) = *(const float4v*)&S[n];
    float P[NS];
#pragma unroll
    for (int n = 0; n < NS; n++) P[n] = exp2f(Al2[n] * sdl);
#pragma unroll
    for (int n = 0; n < NS; n += 4)
        *(float4v*)(Pws + o + n) = *(const float4v*)&P[n];
}

// ---------------- chunk combine (in place): S[c] <- state entering chunk c ----------------
__global__ __launch_bounds__(256) void scan_mid(const float* __restrict__ Pws,
                                                float* __restrict__ Sio) {
    const int i = blockIdx.x * 256 + threadIdx.x;  // over NBATCH*DI*NS
    const int b = i / (DI * NS);
    const int dn = i % (DI * NS);
    float h = 0.f;
#pragma unroll 4
    for (int c = 0; c < NC; ++c) {
        const size_t o = ((size_t)(b * NC + c) * DI * NS) + dn;
        float s = Sio[o];
        float p = Pws[o];
        Sio[o] = h;
        h = fmaf(p, h, s);
    }
}

// ---------------- scan pass 2 (lane-owns-d): re-scan from Hin, emit gated y ----------------
__global__ __launch_bounds__(256) void scan_p2(const float* __restrict__ delta,
                                               const short* __restrict__ ub,
                                               const float* __restrict__ bcf,
                                               const short* __restrict__ alog,
                                               const short* __restrict__ dpar,
                                               const short* __restrict__ resb,
                                               const float* __restrict__ Hin,
                                               short* __restrict__ yb) {
    const int c = blockIdx.x;
    const int b = blockIdx.y / 6;
    const int dblk = blockIdx.y % 6;
    const int d = dblk * 256 + threadIdx.x;

    float Al2[NS];
    {
        short8 a0 = *(const short8*)(alog + (size_t)d * NS);
        short8 a1 = *(const short8*)(alog + (size_t)d * NS + 8);
#pragma unroll
        for (int n = 0; n < 8; n++) {
            Al2[n]     = -__expf(bf2f(a0[n])) * 1.44269504f;
            Al2[n + 8] = -__expf(bf2f(a1[n])) * 1.44269504f;
        }
    }
    const float Dd = bf2f(dpar[d]);
    float h[NS];
    {
        const size_t o = (((size_t)b * NC + c) * DI + d) * NS;
#pragma unroll
        for (int n = 0; n < NS; n += 4)
            *(float4v*)&h[n] = *(const float4v*)(Hin + o + n);
    }
    const size_t tok0 = (size_t)b * LSEQ + (size_t)c * LC;
#pragma unroll 2
    for (int t = 0; t < LC; ++t) {
        const size_t tok = tok0 + t;
        float dl = delta[tok * DI + d];
        float uu = bf2f(ub[tok * DI + d]);
        float rr = bf2f(resb[tok * DI + d]);
        const float* bp = bcf + tok * 32;
        float Bq[NS], Cq[NS];
        *(float4v*)&Bq[0]  = *(const float4v*)(bp);
        *(float4v*)&Bq[4]  = *(const float4v*)(bp + 4);
        *(float4v*)&Bq[8]  = *(const float4v*)(bp + 8);
        *(float4v*)&Bq[12] = *(const float4v*)(bp + 12);
        *(float4v*)&Cq[0]  = *(const float4v*)(bp + 16);
        *(float4v*)&Cq[4]  = *(const float4v*)(bp + 20);
        *(float4v*)&Cq[8]  = *(const float4v*)(bp + 24);
        *(float4v*)&Cq[12] = *(const float4v*)(bp + 28);
        float du = dl * uu;
        float y0 = 0.f, y1 = 0.f, y2 = 0.f, y3 = 0.f;
#pragma unroll
        for (int n = 0; n < NS; n += 4) {
            float a0 = exp2f(dl * Al2[n]);
            float a1 = exp2f(dl * Al2[n + 1]);
            float a2 = exp2f(dl * Al2[n + 2]);
            float a3 = exp2f(dl * Al2[n + 3]);
            h[n]     = fmaf(a0, h[n],     du * Bq[n]);
            h[n + 1] = fmaf(a1, h[n + 1], du * Bq[n + 1]);
            h[n + 2] = fmaf(a2, h[n + 2], du * Bq[n + 2]);
            h[n + 3] = fmaf(a3, h[n + 3], du * Bq[n + 3]);
            y0 = fmaf(h[n],     Cq[n],     y0);
            y1 = fmaf(h[n + 1], Cq[n + 1], y1);
            y2 = fmaf(h[n + 2], Cq[n + 2], y2);
            y3 = fmaf(h[n + 3], Cq[n + 3], y3);
        }
        float y = (y0 + y1) + (y2 + y3) + uu * Dd;
        yb[tok * DI + d] = f2bf(y * silu(rr));
    }
}

extern "C" void kernel_launch(void* const* d_in, const int* in_sizes, int n_in,
                              void* d_out, int out_size, void* d_ws, size_t ws_size,
                              hipStream_t stream) {
    char* ws = (char*)d_ws;
    size_t off = 0;
    auto take = [&](size_t bytes) { char* p = ws + off; off = (off + bytes + 255) & ~(size_t)255; return p; };
    int*   flag = (int*)take(4);
    short* canon = (short*)take((size_t)O_TOT * 2);
    short* xn   = (short*)take((size_t)NT * DM * 2);
    short* xinb = (short*)take((size_t)NT * DI * 2);    // dead after conv; reused as Pws
    short* res  = (short*)take((size_t)NT * DI * 2);
    short* ub   = (short*)take((size_t)NT * DI * 2);
    short* dtb  = (short*)take((size_t)NT * 64 * 2);
    float* bcf  = (float*)take((size_t)NT * 32 * 4);
    short* dtwp = (short*)take((size_t)DI * 64 * 2);
    float* delt = (float*)take((size_t)NT * DI * 4);    // dead after scan_p2; reused as split-K partials
    short* yb   = (short*)take((size_t)NT * DI * 2);
    float* Sws  = (float*)take((size_t)NBATCH * NC * DI * NS * 4);  // doubles as Hin
    // aliases (lifetimes disjoint):
    float* Pws  = (float*)xinb;   // needs 2*64*1536*16*4 B == NT*DI*2 B exactly
    float* part = delt;           // needs 2*NT*DM*4 B == NT*DI*4 B exactly

    const short* cx    = canon + O_X;
    const short* clnw  = canon + O_LNW;
    const short* clnb  = canon + O_LNB;
    const short* cinw  = canon + O_INW;
    const short* ccw   = canon + O_CW;
    const short* ccb   = canon + O_CB;
    const short* cxpw  = canon + O_XPW;
    const short* cdtb  = canon + O_DTB;
    const short* calog = canon + O_ALOG;
    const short* cdpar = canon + O_DPAR;
    const short* coutw = canon + O_OUTW;

    detect_kernel<<<1, 64, 0, stream>>>((const unsigned short*)d_in[0], flag);
    canon_kernel<<<(O_TOT + PAD_EXTRA + 255) / 256, 256, 0, stream>>>(
        d_in[0], d_in[1], d_in[2], d_in[3], d_in[4], d_in[5],
        d_in[6], d_in[7], d_in[8], d_in[9], d_in[10], d_in[11], flag, canon, dtwp);

    ln_kernel<<<NT / 4, 256, 0, stream>>>(cx, clnw, clnb, xn);
    gemm128<0><<<dim3(3072 / 128, NT / 128), 256, 0, stream>>>(xn, cinw, DM, DM, DM,
                                                               nullptr, xinb, res);
    conv_kernel<<<NT * DI / 256, 256, 0, stream>>>(xinb, ccw, ccb, ub);
    gemm_small<<<dim3(2, NT / 64), 256, 0, stream>>>(ub, cxpw, 80, DI, dtb, bcf);
    gemm128<3><<<dim3(DI / 128, NT / 128), 256, 0, stream>>>(dtb, dtwp, 64, 64, 64,
                                                             delt, (short*)cdtb, nullptr);

    scan_p1<<<dim3(NC, NBATCH * 6), 256, 0, stream>>>(delt, ub, bcf, calog, Pws, Sws);
    scan_mid<<<NBATCH * DI * NS / 256, 256, 0, stream>>>(Pws, Sws);
    scan_p2<<<dim3(NC, NBATCH * 6), 256, 0, stream>>>(delt, ub, bcf, calog, cdpar, res, Sws, yb);

    gemm128<4><<<dim3(DM / 128, NT / 128, 2), 256, 0, stream>>>(yb, coutw, DI / 2, DI, DI,
                                                                part, nullptr, nullptr);
    reduce_out<<<NT * DM / 256, 256, 0, stream>>>(part, flag, (float*)d_out, (short*)d_out);
}

// Round 9
// 326.363 us; speedup vs baseline: 5.5247x; 1.0098x over previous
//
#include <hip/hip_runtime.h>

#define NT 4096      // B*L tokens
#define DM 768
#define DI 1536
#define LSEQ 2048
#define NBATCH 2
#define DTR 48
#define NS 16
#define NC 64        // scan chunks
#define LC 32        // chunk length (LSEQ/NC)

// canonical input segment offsets (elements). x (region [0,O_LNW)) is NOT converted
// anymore (LN reads raw), but offsets are kept for address stability.
#define O_X    0
#define O_LNW  3145728
#define O_LNB  3146496
#define O_INW  3147264
#define O_CW   5506560
#define O_CB   5512704
#define O_XPW  5514240
#define O_DTW  5637120
#define O_DTB  5710848
#define O_ALOG 5712384
#define O_DPAR 5736960
#define O_OUTW 5738496
#define O_TOT  6918144
#define PAD_EXTRA (DI * 16)   // zero-fill region for dtwp cols 48..63

typedef __attribute__((ext_vector_type(8))) short short8;
typedef __attribute__((ext_vector_type(4))) float float4v;
typedef __attribute__((ext_vector_type(2))) float float2v;

__device__ __forceinline__ float bf2f(short s) {
    union { unsigned int u; float f; } c; c.u = ((unsigned int)(unsigned short)s) << 16; return c.f;
}
__device__ __forceinline__ float bflo(unsigned int u) {
    union { unsigned int u; float f; } c; c.u = u << 16; return c.f;
}
__device__ __forceinline__ float bfhi(unsigned int u) {
    union { unsigned int u; float f; } c; c.u = u & 0xffff0000u; return c.f;
}
__device__ __forceinline__ short f2bf(float f) {
    union { unsigned int u; float f; } c; c.f = f;
    unsigned int lsb = (c.u >> 16) & 1u;
    unsigned int r = c.u + 0x7fffu + lsb;
    return (short)(r >> 16);
}
__device__ __forceinline__ float silu(float x) { return x / (1.f + __expf(-x)); }

// block-local dtype detect: each wave ballots over x's even shorts (bf16 data:
// exponent plausible ~always; f32 data: mantissa low bits ~uniform).
__device__ __forceinline__ bool detect_f32(const unsigned short* __restrict__ x, int tid) {
    int lane = tid & 63;
    unsigned short s = x[lane * 2];
    int e = (s >> 7) & 0xFF;
    bool plaus = (e >= 100 && e <= 140);
    unsigned long long m = __ballot(plaus);
    return __popcll(m) < 32;   // true => f32 inputs
}

// ------- canonicalize weight inputs into bf16 buffer; also build padded dt_proj_w [1536x64] ----
__global__ __launch_bounds__(256) void canon_kernel(
    const void* sx, const void* s1, const void* s2, const void* s3,
    const void* s4, const void* s5, const void* s6, const void* s7,
    const void* s8, const void* s9, const void* s10, const void* s11,
    short* __restrict__ canon, short* __restrict__ dtwp) {
    const bool isf32 = detect_f32((const unsigned short*)sx, threadIdx.x);
    int i = O_LNW + blockIdx.x * 256 + threadIdx.x;
    if (i >= O_TOT) {
        int i2 = i - O_TOT;
        if (i2 < PAD_EXTRA) dtwp[(i2 >> 4) * 64 + 48 + (i2 & 15)] = 0;
        return;
    }
    const void* src; int j;
    if      (i < O_LNB)  { src = s1;  j = i - O_LNW; }
    else if (i < O_INW)  { src = s2;  j = i - O_LNB; }
    else if (i < O_CW)   { src = s3;  j = i - O_INW; }
    else if (i < O_CB)   { src = s4;  j = i - O_CW; }
    else if (i < O_XPW)  { src = s5;  j = i - O_CB; }
    else if (i < O_DTW)  { src = s6;  j = i - O_XPW; }
    else if (i < O_DTB)  { src = s7;  j = i - O_DTW; }
    else if (i < O_ALOG) { src = s8;  j = i - O_DTB; }
    else if (i < O_DPAR) { src = s9;  j = i - O_ALOG; }
    else if (i < O_OUTW) { src = s10; j = i - O_DPAR; }
    else                 { src = s11; j = i - O_OUTW; }
    short v;
    if (isf32) v = f2bf(((const float*)src)[j]);
    else       v = ((const short*)src)[j];
    canon[i] = v;
    if (i >= O_DTW && i < O_DTB) {
        int jj = i - O_DTW;
        dtwp[(jj / DTR) * 64 + (jj % DTR)] = v;
    }
}

// ---------------- LayerNorm: one wave per token, reads raw x (dtype-branched) ----------------
__global__ __launch_bounds__(256) void ln_kernel(const unsigned short* __restrict__ xraw,
                                                 const short* __restrict__ w,
                                                 const short* __restrict__ b,
                                                 short* __restrict__ xn) {
    const int wave = threadIdx.x >> 6, lane = threadIdx.x & 63;
    const bool isf32 = detect_f32(xraw, threadIdx.x);
    const int token = blockIdx.x * 4 + wave;
    short* xo = xn + (size_t)token * DM;
    float vals[12];
    float s = 0.f, s2 = 0.f;
    if (isf32) {
        const float* xr = (const float*)xraw + (size_t)token * DM;
#pragma unroll
        for (int j = 0; j < 6; j++) {
            float2v f = *(const float2v*)(xr + lane * 2 + j * 128);
            vals[2 * j] = f[0]; vals[2 * j + 1] = f[1];
            s += f[0] + f[1]; s2 += f[0] * f[0] + f[1] * f[1];
        }
    } else {
        const short* xr = (const short*)xraw + (size_t)token * DM;
#pragma unroll
        for (int j = 0; j < 6; j++) {
            unsigned int u = *(const unsigned int*)(xr + lane * 2 + j * 128);
            float f0 = bflo(u), f1 = bfhi(u);
            vals[2 * j] = f0; vals[2 * j + 1] = f1;
            s += f0 + f1; s2 += f0 * f0 + f1 * f1;
        }
    }
#pragma unroll
    for (int off = 1; off < 64; off <<= 1) {
        s += __shfl_xor(s, off);
        s2 += __shfl_xor(s2, off);
    }
    const float mu = s * (1.f / DM);
    const float var = s2 * (1.f / DM) - mu * mu;
    const float rs = rsqrtf(var + 1e-5f);
#pragma unroll
    for (int j = 0; j < 6; j++) {
        int e = lane * 2 + j * 128;
        unsigned int uw = *(const unsigned int*)(w + e);
        unsigned int ub = *(const unsigned int*)(b + e);
        float o0 = (vals[2 * j] - mu) * rs * bflo(uw) + bflo(ub);
        float o1 = (vals[2 * j + 1] - mu) * rs * bfhi(uw) + bfhi(ub);
        unsigned int pk = (unsigned int)(unsigned short)f2bf(o0) |
                          ((unsigned int)(unsigned short)f2bf(o1) << 16);
        *(unsigned int*)(xo + e) = pk;
    }
}

// ---------------- 128x128 bf16 MFMA GEMM with register prefetch ----------------
// C[m,n] = sum_k A[m,k]*B[n,k], row strides lda/ldb.
// MODE 0: in_proj split: n<DI -> outS bf16 (stride DI), else outS2 (stride DI)
// MODE 3: dt_proj: outS2[m*DI+n] = bf16(softplus(v + bias[n])); bias via outS
template <int MODE>
__global__ __launch_bounds__(256) void gemm128(const short* __restrict__ A,
                                               const short* __restrict__ B,
                                               int K, int lda, int ldb,
                                               short* __restrict__ outS,
                                               short* __restrict__ outS2) {
    __shared__ short As[128 * 40];
    __shared__ short Bs[128 * 40];
    const int tid = threadIdx.x;
    const int wave = tid >> 6, lane = tid & 63;
    const int mBase = blockIdx.y * 128, nBase = blockIdx.x * 128;
    const int l15 = lane & 15, quad = lane >> 4;
    const int wm = (wave >> 1) * 64;
    const int wn = (wave & 1) * 64;
    const int srow = tid >> 2;
    const int scol = (tid & 3) * 8;

    const short* aP = A + (size_t)(mBase + srow) * lda + scol;
    const short* bP = B + (size_t)(nBase + srow) * ldb + scol;
    const size_t halfA = (size_t)64 * lda;
    const size_t halfB = (size_t)64 * ldb;

    short8 ra0 = *(const short8*)(aP);
    short8 ra1 = *(const short8*)(aP + halfA);
    short8 rb0 = *(const short8*)(bP);
    short8 rb1 = *(const short8*)(bP + halfB);

    float4v acc[4][4] = {};

    for (int k0 = 0; k0 < K; k0 += 32) {
        __syncthreads();
        *(short8*)&As[srow * 40 + scol] = ra0;
        *(short8*)&As[(srow + 64) * 40 + scol] = ra1;
        *(short8*)&Bs[srow * 40 + scol] = rb0;
        *(short8*)&Bs[(srow + 64) * 40 + scol] = rb1;
        __syncthreads();
        const int k1 = k0 + 32;
        if (k1 < K) {
            ra0 = *(const short8*)(aP + k1);
            ra1 = *(const short8*)(aP + halfA + k1);
            rb0 = *(const short8*)(bP + k1);
            rb1 = *(const short8*)(bP + halfB + k1);
        }
        short8 af[4], bf[4];
#pragma unroll
        for (int i = 0; i < 4; i++) {
            af[i] = *(const short8*)&As[(wm + i * 16 + l15) * 40 + quad * 8];
            bf[i] = *(const short8*)&Bs[(wn + i * 16 + l15) * 40 + quad * 8];
        }
#pragma unroll
        for (int i = 0; i < 4; i++)
#pragma unroll
            for (int j = 0; j < 4; j++)
                acc[i][j] = __builtin_amdgcn_mfma_f32_16x16x32_bf16(af[i], bf[j], acc[i][j], 0, 0, 0);
    }

#pragma unroll
    for (int i = 0; i < 4; i++)
#pragma unroll
        for (int j = 0; j < 4; j++)
#pragma unroll
            for (int r = 0; r < 4; r++) {
                int m = mBase + wm + i * 16 + quad * 4 + r;
                int n = nBase + wn + j * 16 + l15;
                float v = acc[i][j][r];
                if (MODE == 0) {
                    if (n < DI) outS[(size_t)m * DI + n] = f2bf(v);
                    else outS2[(size_t)m * DI + (n - DI)] = f2bf(v);
                } else {
                    float s = v + bf2f(outS[n]);
                    float sp = (s > 20.f) ? s : log1pf(__expf(s));
                    outS2[(size_t)m * DI + n] = f2bf(sp);
                }
            }
}

// ---------------- out_proj: 128x64-tile GEMM, writes d_out directly (dtype-branched) ----------
__global__ __launch_bounds__(256) void gemm_out(const short* __restrict__ A,
                                                const short* __restrict__ B,
                                                const unsigned short* __restrict__ xraw,
                                                void* __restrict__ out) {
    __shared__ short As[128 * 40];
    __shared__ short Bs[64 * 40];
    const int tid = threadIdx.x;
    const int wave = tid >> 6, lane = tid & 63;
    const int mBase = blockIdx.y * 128, nBase = blockIdx.x * 64;
    const int l15 = lane & 15, quad = lane >> 4;
    const int wm = (wave >> 1) * 64;
    const int wn = (wave & 1) * 32;
    const int srow = tid >> 2;
    const int scol = (tid & 3) * 8;

    const short* aP = A + (size_t)(mBase + srow) * DI + scol;
    const short* bP = B + (size_t)(nBase + srow) * DI + scol;
    const size_t halfA = (size_t)64 * DI;

    short8 ra0 = *(const short8*)(aP);
    short8 ra1 = *(const short8*)(aP + halfA);
    short8 rb0 = *(const short8*)(bP);

    float4v acc[4][2] = {};

    for (int k0 = 0; k0 < DI; k0 += 32) {
        __syncthreads();
        *(short8*)&As[srow * 40 + scol] = ra0;
        *(short8*)&As[(srow + 64) * 40 + scol] = ra1;
        *(short8*)&Bs[srow * 40 + scol] = rb0;
        __syncthreads();
        const int k1 = k0 + 32;
        if (k1 < DI) {
            ra0 = *(const short8*)(aP + k1);
            ra1 = *(const short8*)(aP + halfA + k1);
            rb0 = *(const short8*)(bP + k1);
        }
        short8 af[4], bf[2];
#pragma unroll
        for (int i = 0; i < 4; i++)
            af[i] = *(const short8*)&As[(wm + i * 16 + l15) * 40 + quad * 8];
#pragma unroll
        for (int j = 0; j < 2; j++)
            bf[j] = *(const short8*)&Bs[(wn + j * 16 + l15) * 40 + quad * 8];
#pragma unroll
        for (int i = 0; i < 4; i++)
#pragma unroll
            for (int j = 0; j < 2; j++)
                acc[i][j] = __builtin_amdgcn_mfma_f32_16x16x32_bf16(af[i], bf[j], acc[i][j], 0, 0, 0);
    }

    const bool isf32 = detect_f32(xraw, tid);
#pragma unroll
    for (int i = 0; i < 4; i++)
#pragma unroll
        for (int j = 0; j < 2; j++)
#pragma unroll
            for (int r = 0; r < 4; r++) {
                int m = mBase + wm + i * 16 + quad * 4 + r;
                int n = nBase + wn + j * 16 + l15;
                float v = acc[i][j][r];
                if (isf32) ((float*)out)[(size_t)m * DM + n] = v;
                else       ((short*)out)[(size_t)m * DM + n] = f2bf(v);
            }
}

// ---------------- 64-tile GEMM for x_proj (N=80), register prefetch ----------------
__global__ __launch_bounds__(256) void gemm_small(const short* __restrict__ A,
                                                  const short* __restrict__ B,
                                                  int N, int K,
                                                  short* __restrict__ dtb,
                                                  float* __restrict__ bcf) {
    __shared__ short As[64 * 40];
    __shared__ short Bs[64 * 40];
    const int tid = threadIdx.x;
    const int mBase = blockIdx.y * 64;
    const int nBase = blockIdx.x * 64;
    const int lrow = tid >> 2;
    const int lcol = (tid & 3) * 8;
    const int wave = tid >> 6;
    const int lane = tid & 63;
    const int l15 = lane & 15;
    const int quad = lane >> 4;
    const int wm = (wave >> 1) * 32;
    const int wn = (wave & 1) * 32;

    float4v acc[2][2] = {};

    const bool bvalid = (nBase + lrow) < N;
    const short* aptr = A + (size_t)(mBase + lrow) * K + lcol;
    const short* bptr = B + (size_t)(nBase + lrow) * K + lcol;
    const short8 bz = {0, 0, 0, 0, 0, 0, 0, 0};

    short8 av = *(const short8*)(aptr);
    short8 bv = bvalid ? *(const short8*)(bptr) : bz;

    for (int k0 = 0; k0 < K; k0 += 32) {
        __syncthreads();
        *(short8*)&As[lrow * 40 + lcol] = av;
        *(short8*)&Bs[lrow * 40 + lcol] = bv;
        __syncthreads();
        const int k1 = k0 + 32;
        if (k1 < K) {
            av = *(const short8*)(aptr + k1);
            bv = bvalid ? *(const short8*)(bptr + k1) : bz;
        }
        short8 a0 = *(const short8*)&As[(wm + l15) * 40 + quad * 8];
        short8 a1 = *(const short8*)&As[(wm + 16 + l15) * 40 + quad * 8];
        short8 b0 = *(const short8*)&Bs[(wn + l15) * 40 + quad * 8];
        short8 b1 = *(const short8*)&Bs[(wn + 16 + l15) * 40 + quad * 8];
        acc[0][0] = __builtin_amdgcn_mfma_f32_16x16x32_bf16(a0, b0, acc[0][0], 0, 0, 0);
        acc[0][1] = __builtin_amdgcn_mfma_f32_16x16x32_bf16(a0, b1, acc[0][1], 0, 0, 0);
        acc[1][0] = __builtin_amdgcn_mfma_f32_16x16x32_bf16(a1, b0, acc[1][0], 0, 0, 0);
        acc[1][1] = __builtin_amdgcn_mfma_f32_16x16x32_bf16(a1, b1, acc[1][1], 0, 0, 0);
    }

#pragma unroll
    for (int i = 0; i < 2; i++)
#pragma unroll
        for (int j = 0; j < 2; j++)
#pragma unroll
            for (int r = 0; r < 4; r++) {
                int m = mBase + wm + i * 16 + quad * 4 + r;
                int n = nBase + wn + j * 16 + l15;
                float v = acc[i][j][r];
                if (n < DTR) {
                    dtb[(size_t)m * 64 + n] = f2bf(v);
                } else if (n < 64) {
                    dtb[(size_t)m * 64 + n] = (short)0;
                    bcf[(size_t)m * 32 + (n - DTR)] = v;
                } else if (n < 80) {
                    bcf[(size_t)m * 32 + (n - DTR)] = v;
                }
            }
}

// ---------------- depthwise causal conv (taps=4) + SiLU ----------------
__global__ __launch_bounds__(256) void conv_kernel(const short* __restrict__ xin,
                                                   const short* __restrict__ cw,
                                                   const short* __restrict__ cb,
                                                   short* __restrict__ ub) {
    const int idx = blockIdx.x * 256 + threadIdx.x;  // over NT*DI, exact
    const int d = idx % DI;
    const int t = idx / DI;
    const int l = t % LSEQ;
    float s = bf2f(cb[d]);
#pragma unroll
    for (int j = 0; j < 4; j++) {
        int lj = l - 3 + j;
        if (lj >= 0) s += bf2f(xin[(size_t)(t - 3 + j) * DI + d]) * bf2f(cw[d * 4 + j]);
    }
    float u = silu(s);
    ub[idx] = f2bf(u);
}

// ---------------- scan pass 1 (lane-owns-d): chunk summary S, P via log-space ----------------
__global__ __launch_bounds__(256) void scan_p1(const short* __restrict__ delta,
                                               const short* __restrict__ ub,
                                               const float* __restrict__ bcf,
                                               const short* __restrict__ alog,
                                               float* __restrict__ Pws,
                                               float* __restrict__ Sws) {
    const int c = blockIdx.x;
    const int b = blockIdx.y / 6;
    const int dblk = blockIdx.y % 6;
    const int d = dblk * 256 + threadIdx.x;

    float Al2[NS];
    {
        short8 a0 = *(const short8*)(alog + (size_t)d * NS);
        short8 a1 = *(const short8*)(alog + (size_t)d * NS + 8);
#pragma unroll
        for (int n = 0; n < 8; n++) {
            Al2[n]     = -__expf(bf2f(a0[n])) * 1.44269504f;
            Al2[n + 8] = -__expf(bf2f(a1[n])) * 1.44269504f;
        }
    }
    float S[NS];
#pragma unroll
    for (int n = 0; n < NS; n++) S[n] = 0.f;
    float sdl = 0.f;
    const size_t tok0 = (size_t)b * LSEQ + (size_t)c * LC;
#pragma unroll 2
    for (int t = 0; t < LC; ++t) {
        const size_t tok = tok0 + t;
        float dl = bf2f(delta[tok * DI + d]);
        float uu = bf2f(ub[tok * DI + d]);
        const float* bp = bcf + tok * 32;
        float Bq[NS];
        *(float4v*)&Bq[0]  = *(const float4v*)(bp);
        *(float4v*)&Bq[4]  = *(const float4v*)(bp + 4);
        *(float4v*)&Bq[8]  = *(const float4v*)(bp + 8);
        *(float4v*)&Bq[12] = *(const float4v*)(bp + 12);
        float du = dl * uu;
        sdl += dl;
#pragma unroll
        for (int n = 0; n < NS; n++) {
            float a = exp2f(dl * Al2[n]);
            S[n] = fmaf(a, S[n], du * Bq[n]);
        }
    }
    const size_t o = (((size_t)b * NC + c) * DI + d) * NS;
#pragma unroll
    for (int n = 0; n < NS; n += 4)
        *(float4v*)(Sws + o + n) = *(const float4v*)&S[n];
    float P[NS];
#pragma unroll
    for (int n = 0; n < NS; n++) P[n] = exp2f(Al2[n] * sdl);
#pragma unroll
    for (int n = 0; n < NS; n += 4)
        *(float4v*)(Pws + o + n) = *(const float4v*)&P[n];
}

// ---------------- chunk combine (in place): S[c] <- state entering chunk c ----------------
__global__ __launch_bounds__(256) void scan_mid(const float* __restrict__ Pws,
                                                float* __restrict__ Sio) {
    const int i = blockIdx.x * 256 + threadIdx.x;  // over NBATCH*DI*NS
    const int b = i / (DI * NS);
    const int dn = i % (DI * NS);
    float h = 0.f;
#pragma unroll 4
    for (int c = 0; c < NC; ++c) {
        const size_t o = ((size_t)(b * NC + c) * DI * NS) + dn;
        float s = Sio[o];
        float p = Pws[o];
        Sio[o] = h;
        h = fmaf(p, h, s);
    }
}

// ---------------- scan pass 2 (lane-owns-d): re-scan from Hin, emit gated y ----------------
__global__ __launch_bounds__(256) void scan_p2(const short* __restrict__ delta,
                                               const short* __restrict__ ub,
                                               const float* __restrict__ bcf,
                                               const short* __restrict__ alog,
                                               const short* __restrict__ dpar,
                                               const short* __restrict__ resb,
                                               const float* __restrict__ Hin,
                                               short* __restrict__ yb) {
    const int c = blockIdx.x;
    const int b = blockIdx.y / 6;
    const int dblk = blockIdx.y % 6;
    const int d = dblk * 256 + threadIdx.x;

    float Al2[NS];
    {
        short8 a0 = *(const short8*)(alog + (size_t)d * NS);
        short8 a1 = *(const short8*)(alog + (size_t)d * NS + 8);
#pragma unroll
        for (int n = 0; n < 8; n++) {
            Al2[n]     = -__expf(bf2f(a0[n])) * 1.44269504f;
            Al2[n + 8] = -__expf(bf2f(a1[n])) * 1.44269504f;
        }
    }
    const float Dd = bf2f(dpar[d]);
    float h[NS];
    {
        const size_t o = (((size_t)b * NC + c) * DI + d) * NS;
#pragma unroll
        for (int n = 0; n < NS; n += 4)
            *(float4v*)&h[n] = *(const float4v*)(Hin + o + n);
    }
    const size_t tok0 = (size_t)b * LSEQ + (size_t)c * LC;
#pragma unroll 2
    for (int t = 0; t < LC; ++t) {
        const size_t tok = tok0 + t;
        float dl = bf2f(delta[tok * DI + d]);
        float uu = bf2f(ub[tok * DI + d]);
        float rr = bf2f(resb[tok * DI + d]);
        const float* bp = bcf + tok * 32;
        float Bq[NS], Cq[NS];
        *(float4v*)&Bq[0]  = *(const float4v*)(bp);
        *(float4v*)&Bq[4]  = *(const float4v*)(bp + 4);
        *(float4v*)&Bq[8]  = *(const float4v*)(bp + 8);
        *(float4v*)&Bq[12] = *(const float4v*)(bp + 12);
        *(float4v*)&Cq[0]  = *(const float4v*)(bp + 16);
        *(float4v*)&Cq[4]  = *(const float4v*)(bp + 20);
        *(float4v*)&Cq[8]  = *(const float4v*)(bp + 24);
        *(float4v*)&Cq[12] = *(const float4v*)(bp + 28);
        float du = dl * uu;
        float y0 = 0.f, y1 = 0.f, y2 = 0.f, y3 = 0.f;
#pragma unroll
        for (int n = 0; n < NS; n += 4) {
            float a0 = exp2f(dl * Al2[n]);
            float a1 = exp2f(dl * Al2[n + 1]);
            float a2 = exp2f(dl * Al2[n + 2]);
            float a3 = exp2f(dl * Al2[n + 3]);
            h[n]     = fmaf(a0, h[n],     du * Bq[n]);
            h[n + 1] = fmaf(a1, h[n + 1], du * Bq[n + 1]);
            h[n + 2] = fmaf(a2, h[n + 2], du * Bq[n + 2]);
            h[n + 3] = fmaf(a3, h[n + 3], du * Bq[n + 3]);
            y0 = fmaf(h[n],     Cq[n],     y0);
            y1 = fmaf(h[n + 1], Cq[n + 1], y1);
            y2 = fmaf(h[n + 2], Cq[n + 2], y2);
            y3 = fmaf(h[n + 3], Cq[n + 3], y3);
        }
        float y = (y0 + y1) + (y2 + y3) + uu * Dd;
        yb[tok * DI + d] = f2bf(y * silu(rr));
    }
}

extern "C" void kernel_launch(void* const* d_in, const int* in_sizes, int n_in,
                              void* d_out, int out_size, void* d_ws, size_t ws_size,
                              hipStream_t stream) {
    char* ws = (char*)d_ws;
    size_t off = 0;
    auto take = [&](size_t bytes) { char* p = ws + off; off = (off + bytes + 255) & ~(size_t)255; return p; };
    short* canon = (short*)take((size_t)O_TOT * 2);
    short* xn   = (short*)take((size_t)NT * DM * 2);
    short* xinb = (short*)take((size_t)NT * DI * 2);    // dead after conv; reused as Pws
    short* res  = (short*)take((size_t)NT * DI * 2);
    short* ub   = (short*)take((size_t)NT * DI * 2);
    short* dtb  = (short*)take((size_t)NT * 64 * 2);
    float* bcf  = (float*)take((size_t)NT * 32 * 4);
    short* dtwp = (short*)take((size_t)DI * 64 * 2);
    short* delt = (short*)take((size_t)NT * DI * 2);    // bf16 delta
    short* yb   = (short*)take((size_t)NT * DI * 2);
    float* Sws  = (float*)take((size_t)NBATCH * NC * DI * NS * 4);  // doubles as Hin
    float* Pws  = (float*)xinb;   // needs 2*64*1536*16*4 B == NT*DI*2 B exactly

    const short* clnw  = canon + O_LNW;
    const short* clnb  = canon + O_LNB;
    const short* cinw  = canon + O_INW;
    const short* ccw   = canon + O_CW;
    const short* ccb   = canon + O_CB;
    const short* cxpw  = canon + O_XPW;
    const short* cdtb  = canon + O_DTB;
    const short* calog = canon + O_ALOG;
    const short* cdpar = canon + O_DPAR;
    const short* coutw = canon + O_OUTW;
    const unsigned short* xraw = (const unsigned short*)d_in[0];

    canon_kernel<<<(O_TOT - O_LNW + PAD_EXTRA + 255) / 256, 256, 0, stream>>>(
        d_in[0], d_in[1], d_in[2], d_in[3], d_in[4], d_in[5],
        d_in[6], d_in[7], d_in[8], d_in[9], d_in[10], d_in[11], canon, dtwp);

    ln_kernel<<<NT / 4, 256, 0, stream>>>(xraw, clnw, clnb, xn);
    gemm128<0><<<dim3(3072 / 128, NT / 128), 256, 0, stream>>>(xn, cinw, DM, DM, DM, xinb, res);
    conv_kernel<<<NT * DI / 256, 256, 0, stream>>>(xinb, ccw, ccb, ub);
    gemm_small<<<dim3(2, NT / 64), 256, 0, stream>>>(ub, cxpw, 80, DI, dtb, bcf);
    gemm128<3><<<dim3(DI / 128, NT / 128), 256, 0, stream>>>(dtb, dtwp, 64, 64, 64,
                                                             (short*)cdtb, delt);

    scan_p1<<<dim3(NC, NBATCH * 6), 256, 0, stream>>>(delt, ub, bcf, calog, Pws, Sws);
    scan_mid<<<NBATCH * DI * NS / 256, 256, 0, stream>>>(Pws, Sws);
    scan_p2<<<dim3(NC, NBATCH * 6), 256, 0, stream>>>(delt, ub, bcf, calog, cdpar, res, Sws, yb);

    gemm_out<<<dim3(DM / 64, NT / 128), 256, 0, stream>>>(yb, coutw, xraw, d_out);
}